// Round 2
// baseline (712.605 us; speedup 1.0000x reference)
//
#include <hip/hip_runtime.h>
#include <hip/hip_bf16.h>
#include <cstddef>
#include <cstdint>

// ---------------- problem constants ----------------
constexpr int NN = 100000;   // nodes
constexpr int NE = 1600000;  // edges
constexpr int NF = 256;      // in features
constexpr int NH = 128;      // hidden
constexpr int NC = 32;       // classes

// ---------------- CSR build ----------------

__global__ __launch_bounds__(256) void zero_int_kernel(int* __restrict__ p, int n) {
    int i = blockIdx.x * 256 + threadIdx.x;
    if (i < n) p[i] = 0;
}

__global__ __launch_bounds__(256) void copy_int_kernel(const int* __restrict__ src,
                                                       int* __restrict__ dst, int n) {
    int i = blockIdx.x * 256 + threadIdx.x;
    if (i < n) dst[i] = src[i];
}

__global__ __launch_bounds__(256) void hist_kernel(const int* __restrict__ edst,
                                                   int* __restrict__ counts, int ne) {
    int i = blockIdx.x * 256 + threadIdx.x;
    if (i < ne) atomicAdd(&counts[edst[i]], 1);
}

// chunked exclusive scan: CHUNK=1024 elems per block, 256 threads x 4 elems
constexpr int SCAN_CHUNK = 1024;
constexpr int SCAN_NCH = (NN + SCAN_CHUNK - 1) / SCAN_CHUNK;  // 98

__global__ __launch_bounds__(256) void chunk_reduce_kernel(const int* __restrict__ counts,
                                                           int* __restrict__ chunkSums, int n) {
    __shared__ int sdata[256];
    int tid = threadIdx.x;
    int base = blockIdx.x * SCAN_CHUNK + tid * 4;
    int s = 0;
#pragma unroll
    for (int i = 0; i < 4; ++i)
        if (base + i < n) s += counts[base + i];
    sdata[tid] = s;
    __syncthreads();
    for (int off = 128; off > 0; off >>= 1) {
        if (tid < off) sdata[tid] += sdata[tid + off];
        __syncthreads();
    }
    if (tid == 0) chunkSums[blockIdx.x] = sdata[0];
}

__global__ void scan_chunks_kernel(const int* __restrict__ chunkSums,
                                   int* __restrict__ chunkOffs,
                                   int* __restrict__ rowptr, int nch, int n, int total) {
    if (blockIdx.x == 0 && threadIdx.x == 0) {
        int a = 0;
        for (int i = 0; i < nch; ++i) { int t = chunkSums[i]; chunkOffs[i] = a; a += t; }
        rowptr[n] = total;  // total edge count is known statically
    }
}

__global__ __launch_bounds__(256) void chunk_scan_kernel(const int* __restrict__ counts,
                                                         const int* __restrict__ chunkOffs,
                                                         int* __restrict__ rowptr, int n) {
    int tid = threadIdx.x;
    int b = blockIdx.x;
    int base = b * SCAN_CHUNK + tid * 4;
    int v[4];
    int s = 0;
#pragma unroll
    for (int i = 0; i < 4; ++i) {
        v[i] = (base + i < n) ? counts[base + i] : 0;
        s += v[i];
    }
    // wave-inclusive scan of s
    int lane = tid & 63, wid = tid >> 6;
    int x = s;
#pragma unroll
    for (int d = 1; d < 64; d <<= 1) {
        int y = __shfl_up(x, d);
        if (lane >= d) x += y;
    }
    __shared__ int wtot[4];
    if (lane == 63) wtot[wid] = x;
    __syncthreads();
    int woff = 0;
    for (int w = 0; w < wid; ++w) woff += wtot[w];
    int excl = chunkOffs[b] + woff + (x - s);
#pragma unroll
    for (int i = 0; i < 4; ++i) {
        if (base + i < n) rowptr[base + i] = excl;
        excl += v[i];
    }
}

// scatter edges into CSR order, packing (src, val) into one 8B record
__global__ __launch_bounds__(256) void scatter_kernel(const int* __restrict__ esrc,
                                                      const int* __restrict__ edst,
                                                      const float* __restrict__ eval_,
                                                      int* __restrict__ cursor,
                                                      int2* __restrict__ pedge, int ne) {
    int i = blockIdx.x * 256 + threadIdx.x;
    if (i < ne) {
        int d = edst[i];
        int pos = atomicAdd(&cursor[d], 1);
        pedge[pos] = make_int2(esrc[i], __float_as_int(eval_[i]));
    }
}

// ---------------- fp32 tiled GEMM: C[M,N] = A[M,K] @ B[K,N] ----------------

template <int BM, int BN, int BK, int TM, int TN>
__global__ __launch_bounds__(256) void gemm_kernel(const float* __restrict__ A,
                                                   const float* __restrict__ B,
                                                   float* __restrict__ C,
                                                   int M, int N, int K) {
    constexpr int TX = BN / TN;
    constexpr int TY = BM / TM;
    static_assert(TX * TY == 256, "thread count");
    constexpr int LDA = BK + 12;  // 28 floats = 112B: 16B-aligned rows, stride%128B != 0
    __shared__ float As[BM][LDA];
    __shared__ float Bs[BK][BN];

    const int tid = threadIdx.x;
    const int tx = tid % TX;
    const int ty = tid / TX;
    const int m0 = blockIdx.x * BM;
    const int n0 = blockIdx.y * BN;

    float acc[TM][TN] = {};

    for (int k0 = 0; k0 < K; k0 += BK) {
        // A tile: BM x BK
        constexpr int A_F4 = BM * BK / 4;
#pragma unroll
        for (int i = tid; i < A_F4; i += 256) {
            int row = i / (BK / 4);
            int kq = i % (BK / 4);
            float4 v = make_float4(0.f, 0.f, 0.f, 0.f);
            int gr = m0 + row;
            if (gr < M) v = *reinterpret_cast<const float4*>(&A[(size_t)gr * K + k0 + kq * 4]);
            *reinterpret_cast<float4*>(&As[row][kq * 4]) = v;
        }
        // B tile: BK x BN
        constexpr int B_F4 = BK * BN / 4;
#pragma unroll
        for (int i = tid; i < B_F4; i += 256) {
            int row = i / (BN / 4);
            int cq = i % (BN / 4);
            float4 v = *reinterpret_cast<const float4*>(&B[(size_t)(k0 + row) * N + cq * 4]);
            *reinterpret_cast<float4*>(&Bs[row][cq * 4]) = v;
        }
        __syncthreads();

#pragma unroll
        for (int kk = 0; kk < BK; kk += 4) {
            float4 a4[TM];
#pragma unroll
            for (int i = 0; i < TM; ++i)
                a4[i] = *reinterpret_cast<const float4*>(&As[ty * TM + i][kk]);
#pragma unroll
            for (int q = 0; q < 4; ++q) {
                float bv[TN];
#pragma unroll
                for (int j = 0; j < TN; ++j) bv[j] = Bs[kk + q][tx * TN + j];
#pragma unroll
                for (int i = 0; i < TM; ++i) {
                    float av = (q == 0) ? a4[i].x : (q == 1) ? a4[i].y : (q == 2) ? a4[i].z : a4[i].w;
#pragma unroll
                    for (int j = 0; j < TN; ++j) acc[i][j] += av * bv[j];
                }
            }
        }
        __syncthreads();
    }

#pragma unroll
    for (int i = 0; i < TM; ++i) {
        int gr = m0 + ty * TM + i;
        if (gr < M) {
#pragma unroll
            for (int j = 0; j < TN; j += 4) {
                float4 v = make_float4(acc[i][j], acc[i][j + 1], acc[i][j + 2], acc[i][j + 3]);
                *reinterpret_cast<float4*>(&C[(size_t)gr * N + n0 + tx * TN + j]) = v;
            }
        }
    }
}

// ---------------- aggregation (SpMM via CSR) ----------------

// One WAVE per node; lane handles feats [2*lane, 2*lane+1] (float2, 8B/lane).
// A single wave instruction gathers the full 512B support row. Fused bias+relu.
__global__ __launch_bounds__(256) void agg_nh_kernel(const float* __restrict__ support,
                                                     const int* __restrict__ rowptr,
                                                     const int2* __restrict__ pedge,
                                                     const float* __restrict__ bias,
                                                     float* __restrict__ out) {
    const int wid = threadIdx.x >> 6;
    const int lane = threadIdx.x & 63;
    const int node = blockIdx.x * 4 + wid;
    const int beg = rowptr[node];
    const int end = rowptr[node + 1];
    float2 acc = make_float2(0.f, 0.f);
    for (int e = beg; e < end; ++e) {
        int2 ed = pedge[e];                     // wave-broadcast 8B load
        float v = __int_as_float(ed.y);
        float2 xr = *reinterpret_cast<const float2*>(&support[(size_t)ed.x * NH + 2 * lane]);
        acc.x += v * xr.x;
        acc.y += v * xr.y;
    }
    float2 bb = *reinterpret_cast<const float2*>(&bias[2 * lane]);
    acc.x = fmaxf(acc.x + bb.x, 0.f);
    acc.y = fmaxf(acc.y + bb.y, 0.f);
    *reinterpret_cast<float2*>(&out[(size_t)node * NH + 2 * lane]) = acc;
}

// One WAVE per node; lanes 0-31 process edge e, lanes 32-63 edge e+1.
// Halves combined with one shfl_xor(32). Fused bias, no relu.
__global__ __launch_bounds__(256) void agg_nc_kernel(const float* __restrict__ support,
                                                     const int* __restrict__ rowptr,
                                                     const int2* __restrict__ pedge,
                                                     const float* __restrict__ bias,
                                                     float* __restrict__ out) {
    const int wid = threadIdx.x >> 6;
    const int lane = threadIdx.x & 63;
    const int half = lane >> 5;   // which of the 2 in-flight edges
    const int f = lane & 31;      // feature index
    const int node = blockIdx.x * 4 + wid;
    const int beg = rowptr[node];
    const int end = rowptr[node + 1];
    float acc = 0.f;
    for (int e = beg + half; e < end; e += 2) {
        int2 ed = pedge[e];                     // half-wave-broadcast 8B load
        acc += __int_as_float(ed.y) * support[(size_t)ed.x * NC + f];
    }
    acc += __shfl_xor(acc, 32);                 // combine the two edge streams
    if (lane < 32) out[(size_t)node * NC + lane] = acc + bias[lane];
}

// ---------------- launch ----------------

extern "C" void kernel_launch(void* const* d_in, const int* in_sizes, int n_in,
                              void* d_out, int out_size, void* d_ws, size_t ws_size,
                              hipStream_t stream) {
    const float* x = (const float*)d_in[0];
    const int* esrc = (const int*)d_in[1];
    const int* edst = (const int*)d_in[2];
    const float* eval_ = (const float*)d_in[3];
    const float* W1 = (const float*)d_in[4];
    const float* b1 = (const float*)d_in[5];
    const float* W2 = (const float*)d_in[6];
    const float* b2 = (const float*)d_in[7];
    float* out = (float*)d_out;

    // workspace layout (all >=8B-aligned)
    char* ws = (char*)d_ws;
    float* support1 = (float*)(ws + 0);                 // 51,200,000 B (reused as support2)
    float* h = (float*)(ws + 51200000);                 // 51,200,000 B
    int* rowptr = (int*)(ws + 102400000);               // 400,004 B (padded to 400,128)
    int* cursor = (int*)(ws + 102800128);               // 400,000 B
    int2* pedge = (int2*)(ws + 103200128);              // 12,800,000 B
    int* chunkSums = (int*)(ws + 116000128);            // 512 B
    int* chunkOffs = (int*)(ws + 116000640);            // 512 B
    float* support2 = support1;
    (void)ws_size; (void)in_sizes; (void)n_in; (void)out_size;

    // ---- CSR build ----
    int* counts = cursor;  // cursor buffer doubles as counts scratch first
    zero_int_kernel<<<(NN + 255) / 256, 256, 0, stream>>>(counts, NN);
    hist_kernel<<<(NE + 255) / 256, 256, 0, stream>>>(edst, counts, NE);
    chunk_reduce_kernel<<<SCAN_NCH, 256, 0, stream>>>(counts, chunkSums, NN);
    scan_chunks_kernel<<<1, 64, 0, stream>>>(chunkSums, chunkOffs, rowptr, SCAN_NCH, NN, NE);
    chunk_scan_kernel<<<SCAN_NCH, 256, 0, stream>>>(counts, chunkOffs, rowptr, NN);
    // cursor <- rowptr (counts buffer dead now; overwrite it)
    copy_int_kernel<<<(NN + 255) / 256, 256, 0, stream>>>(rowptr, cursor, NN);
    scatter_kernel<<<(NE + 255) / 256, 256, 0, stream>>>(esrc, edst, eval_, cursor, pedge, NE);

    // ---- layer 1: support1 = x @ W1 ; h = relu(Agg(support1) + b1) ----
    {
        dim3 grid((NN + 63) / 64, NH / 128);
        gemm_kernel<64, 128, 16, 4, 8><<<grid, 256, 0, stream>>>(x, W1, support1, NN, NH, NF);
    }
    agg_nh_kernel<<<NN / 4, 256, 0, stream>>>(support1, rowptr, pedge, b1, h);

    // ---- layer 2: support2 = h @ W2 ; out = Agg(support2) + b2 ----
    {
        dim3 grid((NN + 127) / 128, NC / 32);
        gemm_kernel<128, 32, 16, 4, 4><<<grid, 256, 0, stream>>>(h, W2, support2, NN, NC, NH);
    }
    agg_nc_kernel<<<NN / 4, 256, 0, stream>>>(support2, rowptr, pedge, b2, out);
}

// Round 3
// 625.893 us; speedup vs baseline: 1.1385x; 1.1385x over previous
//
#include <hip/hip_runtime.h>
#include <hip/hip_bf16.h>
#include <cstddef>
#include <cstdint>

// ---------------- problem constants ----------------
constexpr int NN = 100000;   // nodes
constexpr int NE = 1600000;  // edges
constexpr int NF = 256;      // in features
constexpr int NH = 128;      // hidden
constexpr int NC = 32;       // classes

// ---------------- CSR build ----------------

__global__ __launch_bounds__(256) void zero_int_kernel(int* __restrict__ p, int n) {
    int i = blockIdx.x * 256 + threadIdx.x;
    if (i < n) p[i] = 0;
}

__global__ __launch_bounds__(256) void hist_kernel(const int* __restrict__ edst,
                                                   int* __restrict__ counts, int ne) {
    int i = blockIdx.x * 256 + threadIdx.x;
    if (i < ne) atomicAdd(&counts[edst[i]], 1);
}

// chunked exclusive scan: CHUNK=1024 elems per block, 256 threads x 4 elems
constexpr int SCAN_CHUNK = 1024;
constexpr int SCAN_NCH = (NN + SCAN_CHUNK - 1) / SCAN_CHUNK;  // 98

__global__ __launch_bounds__(256) void chunk_reduce_kernel(const int* __restrict__ counts,
                                                           int* __restrict__ chunkSums, int n) {
    __shared__ int sdata[256];
    int tid = threadIdx.x;
    int base = blockIdx.x * SCAN_CHUNK + tid * 4;
    int s = 0;
#pragma unroll
    for (int i = 0; i < 4; ++i)
        if (base + i < n) s += counts[base + i];
    sdata[tid] = s;
    __syncthreads();
    for (int off = 128; off > 0; off >>= 1) {
        if (tid < off) sdata[tid] += sdata[tid + off];
        __syncthreads();
    }
    if (tid == 0) chunkSums[blockIdx.x] = sdata[0];
}

__global__ void scan_chunks_kernel(const int* __restrict__ chunkSums,
                                   int* __restrict__ chunkOffs,
                                   int* __restrict__ rowptr, int nch, int n, int total) {
    if (blockIdx.x == 0 && threadIdx.x == 0) {
        int a = 0;
        for (int i = 0; i < nch; ++i) { int t = chunkSums[i]; chunkOffs[i] = a; a += t; }
        rowptr[n] = total;  // total edge count is known statically
    }
}

// writes BOTH rowptr and cursor (cursor starts equal to rowptr)
__global__ __launch_bounds__(256) void chunk_scan_kernel(const int* __restrict__ counts,
                                                         const int* __restrict__ chunkOffs,
                                                         int* __restrict__ rowptr,
                                                         int* __restrict__ cursor, int n) {
    int tid = threadIdx.x;
    int b = blockIdx.x;
    int base = b * SCAN_CHUNK + tid * 4;
    int v[4];
    int s = 0;
#pragma unroll
    for (int i = 0; i < 4; ++i) {
        v[i] = (base + i < n) ? counts[base + i] : 0;
        s += v[i];
    }
    // wave-inclusive scan of s
    int lane = tid & 63, wid = tid >> 6;
    int x = s;
#pragma unroll
    for (int d = 1; d < 64; d <<= 1) {
        int y = __shfl_up(x, d);
        if (lane >= d) x += y;
    }
    __shared__ int wtot[4];
    if (lane == 63) wtot[wid] = x;
    __syncthreads();
    int woff = 0;
    for (int w = 0; w < wid; ++w) woff += wtot[w];
    int excl = chunkOffs[b] + woff + (x - s);
#pragma unroll
    for (int i = 0; i < 4; ++i) {
        if (base + i < n) { rowptr[base + i] = excl; cursor[base + i] = excl; }
        excl += v[i];
    }
}

// scatter edges into CSR order, packing (src, val) into one 8B record
__global__ __launch_bounds__(256) void scatter_kernel(const int* __restrict__ esrc,
                                                      const int* __restrict__ edst,
                                                      const float* __restrict__ eval_,
                                                      int* __restrict__ cursor,
                                                      int2* __restrict__ pedge, int ne) {
    int i = blockIdx.x * 256 + threadIdx.x;
    if (i < ne) {
        int d = edst[i];
        int pos = atomicAdd(&cursor[d], 1);
        pedge[pos] = make_int2(esrc[i], __float_as_int(eval_[i]));
    }
}

// ---------------- fp32 tiled GEMM: C[M,N] = A[M,K] @ B[K,N] ----------------

template <int BM, int BN, int BK, int TM, int TN>
__global__ __launch_bounds__(256) void gemm_kernel(const float* __restrict__ A,
                                                   const float* __restrict__ B,
                                                   float* __restrict__ C,
                                                   int M, int N, int K) {
    constexpr int TX = BN / TN;
    constexpr int TY = BM / TM;
    static_assert(TX * TY == 256, "thread count");
    constexpr int LDA = BK + 12;  // 28 floats = 112B: 16B-aligned rows, stride%128B != 0
    __shared__ float As[BM][LDA];
    __shared__ float Bs[BK][BN];

    const int tid = threadIdx.x;
    const int tx = tid % TX;
    const int ty = tid / TX;
    const int m0 = blockIdx.x * BM;
    const int n0 = blockIdx.y * BN;

    float acc[TM][TN] = {};

    for (int k0 = 0; k0 < K; k0 += BK) {
        // A tile: BM x BK
        constexpr int A_F4 = BM * BK / 4;
#pragma unroll
        for (int i = tid; i < A_F4; i += 256) {
            int row = i / (BK / 4);
            int kq = i % (BK / 4);
            float4 v = make_float4(0.f, 0.f, 0.f, 0.f);
            int gr = m0 + row;
            if (gr < M) v = *reinterpret_cast<const float4*>(&A[(size_t)gr * K + k0 + kq * 4]);
            *reinterpret_cast<float4*>(&As[row][kq * 4]) = v;
        }
        // B tile: BK x BN
        constexpr int B_F4 = BK * BN / 4;
#pragma unroll
        for (int i = tid; i < B_F4; i += 256) {
            int row = i / (BN / 4);
            int cq = i % (BN / 4);
            float4 v = *reinterpret_cast<const float4*>(&B[(size_t)(k0 + row) * N + cq * 4]);
            *reinterpret_cast<float4*>(&Bs[row][cq * 4]) = v;
        }
        __syncthreads();

#pragma unroll
        for (int kk = 0; kk < BK; ++kk) {
            float a_[TM];
#pragma unroll
            for (int i = 0; i < TM; ++i) a_[i] = As[ty * TM + i][kk];
            float b_[TN];
#pragma unroll
            for (int j = 0; j < TN; j += 4) {
                float4 bv = *reinterpret_cast<const float4*>(&Bs[kk][tx * TN + j]);
                b_[j] = bv.x; b_[j + 1] = bv.y; b_[j + 2] = bv.z; b_[j + 3] = bv.w;
            }
#pragma unroll
            for (int i = 0; i < TM; ++i)
#pragma unroll
                for (int j = 0; j < TN; ++j) acc[i][j] += a_[i] * b_[j];
        }
        __syncthreads();
    }

#pragma unroll
    for (int i = 0; i < TM; ++i) {
        int gr = m0 + ty * TM + i;
        if (gr < M) {
#pragma unroll
            for (int j = 0; j < TN; j += 4) {
                float4 v = make_float4(acc[i][j], acc[i][j + 1], acc[i][j + 2], acc[i][j + 3]);
                *reinterpret_cast<float4*>(&C[(size_t)gr * N + n0 + tx * TN + j]) = v;
            }
        }
    }
}

// ---------------- aggregation (SpMM via CSR) ----------------

// One WAVE per node. 2 half-waves x float4/lane (32 lanes x 16B = full 512B row),
// manually unrolled 2-deep -> 4 independent gathers in flight per wave.
__global__ __launch_bounds__(256) void agg_nh_kernel(const float* __restrict__ support,
                                                     const int* __restrict__ rowptr,
                                                     const int2* __restrict__ pedge,
                                                     const float* __restrict__ bias,
                                                     float* __restrict__ out) {
    const int wid = threadIdx.x >> 6;
    const int lane = threadIdx.x & 63;
    const int g = lane >> 5;      // half-wave id: edge stream parity
    const int f4 = lane & 31;     // float4 index within the 128-float row
    const int node = blockIdx.x * 4 + wid;
    const int beg = rowptr[node];
    const int end = rowptr[node + 1];

    float4 acc0 = make_float4(0.f, 0.f, 0.f, 0.f);
    float4 acc1 = make_float4(0.f, 0.f, 0.f, 0.f);

    int e = beg + g;
    for (; e + 2 < end; e += 4) {   // this half-wave: edges e and e+2
        int2 ed0 = pedge[e];
        int2 ed1 = pedge[e + 2];
        float4 x0 = reinterpret_cast<const float4*>(&support[(size_t)ed0.x * NH])[f4];
        float4 x1 = reinterpret_cast<const float4*>(&support[(size_t)ed1.x * NH])[f4];
        float v0 = __int_as_float(ed0.y);
        float v1 = __int_as_float(ed1.y);
        acc0.x += v0 * x0.x; acc0.y += v0 * x0.y; acc0.z += v0 * x0.z; acc0.w += v0 * x0.w;
        acc1.x += v1 * x1.x; acc1.y += v1 * x1.y; acc1.z += v1 * x1.z; acc1.w += v1 * x1.w;
    }
    for (; e < end; e += 2) {
        int2 ed = pedge[e];
        float4 xr = reinterpret_cast<const float4*>(&support[(size_t)ed.x * NH])[f4];
        float v = __int_as_float(ed.y);
        acc0.x += v * xr.x; acc0.y += v * xr.y; acc0.z += v * xr.z; acc0.w += v * xr.w;
    }

    acc0.x += acc1.x; acc0.y += acc1.y; acc0.z += acc1.z; acc0.w += acc1.w;
    acc0.x += __shfl_xor(acc0.x, 32);
    acc0.y += __shfl_xor(acc0.y, 32);
    acc0.z += __shfl_xor(acc0.z, 32);
    acc0.w += __shfl_xor(acc0.w, 32);

    if (g == 0) {
        float4 bb = reinterpret_cast<const float4*>(bias)[f4];
        float4 r;
        r.x = fmaxf(acc0.x + bb.x, 0.f);
        r.y = fmaxf(acc0.y + bb.y, 0.f);
        r.z = fmaxf(acc0.z + bb.z, 0.f);
        r.w = fmaxf(acc0.w + bb.w, 0.f);
        reinterpret_cast<float4*>(&out[(size_t)node * NH])[f4] = r;
    }
}

// One WAVE per node. 8 groups of 8 lanes x float4 (8 x 16B = full 128B row)
// -> 8 independent gathers in flight per wave. Fused bias, no relu.
__global__ __launch_bounds__(256) void agg_nc_kernel(const float* __restrict__ support,
                                                     const int* __restrict__ rowptr,
                                                     const int2* __restrict__ pedge,
                                                     const float* __restrict__ bias,
                                                     float* __restrict__ out) {
    const int wid = threadIdx.x >> 6;
    const int lane = threadIdx.x & 63;
    const int g = lane >> 3;      // 8 edge streams
    const int f4 = lane & 7;      // float4 index within the 32-float row
    const int node = blockIdx.x * 4 + wid;
    const int beg = rowptr[node];
    const int end = rowptr[node + 1];

    float4 acc = make_float4(0.f, 0.f, 0.f, 0.f);
    for (int e = beg + g; e < end; e += 8) {
        int2 ed = pedge[e];
        float4 xr = reinterpret_cast<const float4*>(&support[(size_t)ed.x * NC])[f4];
        float v = __int_as_float(ed.y);
        acc.x += v * xr.x; acc.y += v * xr.y; acc.z += v * xr.z; acc.w += v * xr.w;
    }
#pragma unroll
    for (int d = 8; d < 64; d <<= 1) {
        acc.x += __shfl_xor(acc.x, d);
        acc.y += __shfl_xor(acc.y, d);
        acc.z += __shfl_xor(acc.z, d);
        acc.w += __shfl_xor(acc.w, d);
    }
    if (lane < 8) {
        float4 bb = reinterpret_cast<const float4*>(bias)[f4];
        float4 r;
        r.x = acc.x + bb.x; r.y = acc.y + bb.y; r.z = acc.z + bb.z; r.w = acc.w + bb.w;
        reinterpret_cast<float4*>(&out[(size_t)node * NC])[f4] = r;
    }
}

// ---------------- launch ----------------

extern "C" void kernel_launch(void* const* d_in, const int* in_sizes, int n_in,
                              void* d_out, int out_size, void* d_ws, size_t ws_size,
                              hipStream_t stream) {
    const float* x = (const float*)d_in[0];
    const int* esrc = (const int*)d_in[1];
    const int* edst = (const int*)d_in[2];
    const float* eval_ = (const float*)d_in[3];
    const float* W1 = (const float*)d_in[4];
    const float* b1 = (const float*)d_in[5];
    const float* W2 = (const float*)d_in[6];
    const float* b2 = (const float*)d_in[7];
    float* out = (float*)d_out;

    // workspace layout (all >=16B-aligned)
    char* ws = (char*)d_ws;
    float* support1 = (float*)(ws + 0);                 // 51,200,000 B (reused as support2)
    float* h = (float*)(ws + 51200000);                 // 51,200,000 B
    int* rowptr = (int*)(ws + 102400000);               // 400,004 B (padded to 400,128)
    int* cursor = (int*)(ws + 102800128);               // 400,000 B
    int2* pedge = (int2*)(ws + 103200128);              // 12,800,000 B
    int* chunkSums = (int*)(ws + 116000128);            // 512 B
    int* chunkOffs = (int*)(ws + 116000640);            // 512 B
    float* support2 = support1;
    (void)ws_size; (void)in_sizes; (void)n_in; (void)out_size;

    // ---- CSR build ----
    int* counts = cursor;  // cursor buffer doubles as counts scratch first
    zero_int_kernel<<<(NN + 255) / 256, 256, 0, stream>>>(counts, NN);
    hist_kernel<<<(NE + 255) / 256, 256, 0, stream>>>(edst, counts, NE);
    chunk_reduce_kernel<<<SCAN_NCH, 256, 0, stream>>>(counts, chunkSums, NN);
    scan_chunks_kernel<<<1, 64, 0, stream>>>(chunkSums, chunkOffs, rowptr, SCAN_NCH, NN, NE);
    chunk_scan_kernel<<<SCAN_NCH, 256, 0, stream>>>(counts, chunkOffs, rowptr, cursor, NN);
    scatter_kernel<<<(NE + 255) / 256, 256, 0, stream>>>(esrc, edst, eval_, cursor, pedge, NE);

    // ---- layer 1: support1 = x @ W1 ; h = relu(Agg(support1) + b1) ----
    {
        dim3 grid((NN + 127) / 128, NH / 128);
        gemm_kernel<128, 128, 16, 8, 8><<<grid, 256, 0, stream>>>(x, W1, support1, NN, NH, NF);
    }
    agg_nh_kernel<<<NN / 4, 256, 0, stream>>>(support1, rowptr, pedge, b1, h);

    // ---- layer 2: support2 = h @ W2 ; out = Agg(support2) + b2 ----
    {
        dim3 grid((NN + 127) / 128, NC / 32);
        gemm_kernel<128, 32, 16, 4, 4><<<grid, 256, 0, stream>>>(h, W2, support2, NN, NC, NH);
    }
    agg_nc_kernel<<<NN / 4, 256, 0, stream>>>(support2, rowptr, pedge, b2, out);
}

// Round 5
// 560.286 us; speedup vs baseline: 1.2719x; 1.1171x over previous
//
#include <hip/hip_runtime.h>
#include <hip/hip_bf16.h>
#include <cstddef>
#include <cstdint>

// ---------------- problem constants ----------------
constexpr int NN = 100000;   // nodes
constexpr int NE = 1600000;  // edges
constexpr int NF = 256;      // in features
constexpr int NH = 128;      // hidden
constexpr int NC = 32;       // classes

typedef __attribute__((ext_vector_type(8))) short short8v;   // 8 bf16 = 4 VGPR
typedef __attribute__((ext_vector_type(16))) float f32x16;   // MFMA 32x32 acc

// round-to-nearest-even fp32 -> bf16 split: a ~= hi + lo, |err| <~ 2^-17 |a|
__device__ inline void bf16split(float a, unsigned short& h, unsigned short& l) {
    unsigned int ab = __float_as_uint(a);
    unsigned int r = ab + 0x7FFFu + ((ab >> 16) & 1u);
    h = (unsigned short)(r >> 16);
    float hf = __uint_as_float((unsigned int)h << 16);
    float res = a - hf;
    unsigned int rb = __float_as_uint(res);
    unsigned int r2 = rb + 0x7FFFu + ((rb >> 16) & 1u);
    l = (unsigned short)(r2 >> 16);
}

// ---------------- CSR build ----------------

__global__ __launch_bounds__(256) void zero_int_kernel(int* __restrict__ p, int n) {
    int i = blockIdx.x * 256 + threadIdx.x;
    if (i < n) p[i] = 0;
}

__global__ __launch_bounds__(256) void hist_kernel(const int* __restrict__ edst,
                                                   int* __restrict__ counts, int ne) {
    int i = blockIdx.x * 256 + threadIdx.x;
    if (i < ne) atomicAdd(&counts[edst[i]], 1);
}

constexpr int SCAN_CHUNK = 1024;
constexpr int SCAN_NCH = (NN + SCAN_CHUNK - 1) / SCAN_CHUNK;  // 98

__global__ __launch_bounds__(256) void chunk_reduce_kernel(const int* __restrict__ counts,
                                                           int* __restrict__ chunkSums, int n) {
    __shared__ int sdata[256];
    int tid = threadIdx.x;
    int base = blockIdx.x * SCAN_CHUNK + tid * 4;
    int s = 0;
#pragma unroll
    for (int i = 0; i < 4; ++i)
        if (base + i < n) s += counts[base + i];
    sdata[tid] = s;
    __syncthreads();
    for (int off = 128; off > 0; off >>= 1) {
        if (tid < off) sdata[tid] += sdata[tid + off];
        __syncthreads();
    }
    if (tid == 0) chunkSums[blockIdx.x] = sdata[0];
}

__global__ void scan_chunks_kernel(const int* __restrict__ chunkSums,
                                   int* __restrict__ chunkOffs,
                                   int* __restrict__ rowptr, int nch, int n, int total) {
    if (blockIdx.x == 0 && threadIdx.x == 0) {
        int a = 0;
        for (int i = 0; i < nch; ++i) { int t = chunkSums[i]; chunkOffs[i] = a; a += t; }
        rowptr[n] = total;
    }
}

// writes BOTH rowptr and cursor (cursor starts equal to rowptr)
__global__ __launch_bounds__(256) void chunk_scan_kernel(const int* __restrict__ counts,
                                                         const int* __restrict__ chunkOffs,
                                                         int* __restrict__ rowptr,
                                                         int* __restrict__ cursor, int n) {
    int tid = threadIdx.x;
    int b = blockIdx.x;
    int base = b * SCAN_CHUNK + tid * 4;
    int v[4];
    int s = 0;
#pragma unroll
    for (int i = 0; i < 4; ++i) {
        v[i] = (base + i < n) ? counts[base + i] : 0;
        s += v[i];
    }
    int lane = tid & 63, wid = tid >> 6;
    int x = s;
#pragma unroll
    for (int d = 1; d < 64; d <<= 1) {
        int y = __shfl_up(x, d);
        if (lane >= d) x += y;
    }
    __shared__ int wtot[4];
    if (lane == 63) wtot[wid] = x;
    __syncthreads();
    int woff = 0;
    for (int w = 0; w < wid; ++w) woff += wtot[w];
    int excl = chunkOffs[b] + woff + (x - s);
#pragma unroll
    for (int i = 0; i < 4; ++i) {
        if (base + i < n) { rowptr[base + i] = excl; cursor[base + i] = excl; }
        excl += v[i];
    }
}

__global__ __launch_bounds__(256) void scatter_kernel(const int* __restrict__ esrc,
                                                      const int* __restrict__ edst,
                                                      const float* __restrict__ eval_,
                                                      int* __restrict__ cursor,
                                                      int2* __restrict__ pedge, int ne) {
    int i = blockIdx.x * 256 + threadIdx.x;
    if (i < ne) {
        int d = edst[i];
        int pos = atomicAdd(&cursor[d], 1);
        pedge[pos] = make_int2(esrc[i], __float_as_int(eval_[i]));
    }
}

// ---------------- weight transpose + bf16 split (once per launch, tiny) ----------------
// W1[NF][NH] -> W1t hi/lo [NH][NF];  W2[NH][NC] -> W2t hi/lo [NC][NH]
__global__ __launch_bounds__(256) void wconv_kernel(const float* __restrict__ W1,
                                                    const float* __restrict__ W2,
                                                    unsigned short* __restrict__ w1h,
                                                    unsigned short* __restrict__ w1l,
                                                    unsigned short* __restrict__ w2h,
                                                    unsigned short* __restrict__ w2l) {
    int i = blockIdx.x * 256 + threadIdx.x;
    if (i < NF * NH) {
        int k = i / NH, n = i % NH;
        unsigned short h, l;
        bf16split(W1[i], h, l);
        w1h[n * NF + k] = h;
        w1l[n * NF + k] = l;
    } else if (i < NF * NH + NH * NC) {
        int j = i - NF * NH;
        int k = j / NC, n = j % NC;
        unsigned short h, l;
        bf16split(W2[j], h, l);
        w2h[n * NH + k] = h;
        w2l[n * NH + k] = l;
    }
}

// ---------------- bf16-split MFMA GEMM: C[M,N] = A[M,K] @ B[K,N] ----------------
// B supplied pre-transposed+split: Bth/Btl [N][K] bf16. fp32 A converted in-kernel.
// Wave tile: RT x CT tiles of 32x32 (mfma_f32_32x32x16_bf16), 3 split-MFMAs per tile.
// LDS holds fragment-ordered A/B slices: frag read = ds_read_b128 at base+lane*16.
template <int WM, int WN, int RT, int CT, int K>
__global__ __launch_bounds__(WM * WN * 64) void gemm_mfma_kernel(
    const float* __restrict__ A,
    const unsigned short* __restrict__ Bth,
    const unsigned short* __restrict__ Btl,
    float* __restrict__ C, int M) {
    constexpr int NTHREADS = WM * WN * 64;
    constexpr int BM = WM * RT * 32;
    constexpr int BN = WN * CT * 32;
    constexpr int ATILES = WM * RT;
    constexpr int BTILES = WN * CT;
    constexpr int A_HI = 0;
    constexpr int A_LO = ATILES * 1024;
    constexpr int B_HI = 2 * ATILES * 1024;
    constexpr int B_LO = B_HI + BTILES * 1024;
    __shared__ __align__(16) unsigned char smem[B_LO + BTILES * 1024];

    const int tid = threadIdx.x;
    const int lane = tid & 63;
    const int w = tid >> 6;
    const int wm = w % WM;
    const int wn = w / WM;
    const int m0 = blockIdx.x * BM;

    f32x16 acc[RT][CT];
#pragma unroll
    for (int r = 0; r < RT; ++r)
#pragma unroll
        for (int c = 0; c < CT; ++c) acc[r][c] = (f32x16)(0.0f);

    for (int k0 = 0; k0 < K; k0 += 16) {
        // ---- stage A: BM x 16 fp32 -> bf16 hi/lo, fragment-ordered ----
#pragma unroll
        for (int idx = tid; idx < BM * 4; idx += NTHREADS) {
            int row = idx >> 2, kq = idx & 3;
            int grow = m0 + row;
            float4 v = make_float4(0.f, 0.f, 0.f, 0.f);
            if (grow < M) v = *reinterpret_cast<const float4*>(&A[(size_t)grow * K + k0 + kq * 4]);
            unsigned short h0, h1, h2, h3, l0, l1, l2, l3;
            bf16split(v.x, h0, l0);
            bf16split(v.y, h1, l1);
            bf16split(v.z, h2, l2);
            bf16split(v.w, h3, l3);
            uint2 hh, ll;
            hh.x = (unsigned)h0 | ((unsigned)h1 << 16);
            hh.y = (unsigned)h2 | ((unsigned)h3 << 16);
            ll.x = (unsigned)l0 | ((unsigned)l1 << 16);
            ll.y = (unsigned)l2 | ((unsigned)l3 << 16);
            // frag slot: tile = row/32, kg = kq>>1, m = row&31, j0 = (kq&1)*4
            int off = (row >> 5) * 1024 + (kq >> 1) * 512 + (row & 31) * 16 + (kq & 1) * 8;
            *reinterpret_cast<uint2*>(&smem[A_HI + off]) = hh;
            *reinterpret_cast<uint2*>(&smem[A_LO + off]) = ll;
        }
        // ---- stage B: BN x 16 bf16 hi/lo (already split), fragment-ordered ----
#pragma unroll
        for (int idx = tid; idx < BN * 2; idx += NTHREADS) {
            int n = idx >> 1, kg = idx & 1;
            uint4 vh = *reinterpret_cast<const uint4*>(&Bth[(size_t)n * K + k0 + kg * 8]);
            uint4 vl = *reinterpret_cast<const uint4*>(&Btl[(size_t)n * K + k0 + kg * 8]);
            int off = (n >> 5) * 1024 + kg * 512 + (n & 31) * 16;
            *reinterpret_cast<uint4*>(&smem[B_HI + off]) = vh;
            *reinterpret_cast<uint4*>(&smem[B_LO + off]) = vl;
        }
        __syncthreads();

        short8v ah[RT], al[RT], bh[CT], bl[CT];
#pragma unroll
        for (int r = 0; r < RT; ++r) {
            int off = (wm * RT + r) * 1024 + lane * 16;
            ah[r] = *reinterpret_cast<const short8v*>(&smem[A_HI + off]);
            al[r] = *reinterpret_cast<const short8v*>(&smem[A_LO + off]);
        }
#pragma unroll
        for (int c = 0; c < CT; ++c) {
            int off = (wn * CT + c) * 1024 + lane * 16;
            bh[c] = *reinterpret_cast<const short8v*>(&smem[B_HI + off]);
            bl[c] = *reinterpret_cast<const short8v*>(&smem[B_LO + off]);
        }
#pragma unroll
        for (int r = 0; r < RT; ++r)
#pragma unroll
            for (int c = 0; c < CT; ++c) {
                acc[r][c] = __builtin_amdgcn_mfma_f32_32x32x16_bf16(ah[r], bh[c], acc[r][c], 0, 0, 0);
                acc[r][c] = __builtin_amdgcn_mfma_f32_32x32x16_bf16(al[r], bh[c], acc[r][c], 0, 0, 0);
                acc[r][c] = __builtin_amdgcn_mfma_f32_32x32x16_bf16(ah[r], bl[c], acc[r][c], 0, 0, 0);
            }
        __syncthreads();
    }

    // ---- epilogue: C[row][col], col=lane&31, row=(reg&3)+8*(reg>>2)+4*(lane>>5) ----
    const int lo32 = lane & 31;
    const int hi32 = lane >> 5;
#pragma unroll
    for (int r = 0; r < RT; ++r)
#pragma unroll
        for (int c = 0; c < CT; ++c) {
            int rowbase = m0 + (wm * RT + r) * 32 + 4 * hi32;
            int col = (wn * CT + c) * 32 + lo32;
#pragma unroll
            for (int g = 0; g < 4; ++g)
#pragma unroll
                for (int q = 0; q < 4; ++q) {
                    int row = rowbase + 8 * g + q;
                    if (row < M) C[(size_t)row * BN + col] = acc[r][c][g * 4 + q];
                }
        }
}

// ---------------- aggregation (SpMM via CSR) ----------------

// One WAVE per node. 2 half-waves x float4/lane (32 lanes x 16B = full 512B row),
// 2-deep unroll -> 4 independent gathers in flight per wave. Fused bias+relu.
__global__ __launch_bounds__(256) void agg_nh_kernel(const float* __restrict__ support,
                                                     const int* __restrict__ rowptr,
                                                     const int2* __restrict__ pedge,
                                                     const float* __restrict__ bias,
                                                     float* __restrict__ out) {
    const int wid = threadIdx.x >> 6;
    const int lane = threadIdx.x & 63;
    const int g = lane >> 5;
    const int f4 = lane & 31;
    const int node = blockIdx.x * 4 + wid;
    const int beg = rowptr[node];
    const int end = rowptr[node + 1];

    float4 acc0 = make_float4(0.f, 0.f, 0.f, 0.f);
    float4 acc1 = make_float4(0.f, 0.f, 0.f, 0.f);

    int e = beg + g;
    for (; e + 2 < end; e += 4) {
        int2 ed0 = pedge[e];
        int2 ed1 = pedge[e + 2];
        float4 x0 = reinterpret_cast<const float4*>(&support[(size_t)ed0.x * NH])[f4];
        float4 x1 = reinterpret_cast<const float4*>(&support[(size_t)ed1.x * NH])[f4];
        float v0 = __int_as_float(ed0.y);
        float v1 = __int_as_float(ed1.y);
        acc0.x += v0 * x0.x; acc0.y += v0 * x0.y; acc0.z += v0 * x0.z; acc0.w += v0 * x0.w;
        acc1.x += v1 * x1.x; acc1.y += v1 * x1.y; acc1.z += v1 * x1.z; acc1.w += v1 * x1.w;
    }
    for (; e < end; e += 2) {
        int2 ed = pedge[e];
        float4 xr = reinterpret_cast<const float4*>(&support[(size_t)ed.x * NH])[f4];
        float v = __int_as_float(ed.y);
        acc0.x += v * xr.x; acc0.y += v * xr.y; acc0.z += v * xr.z; acc0.w += v * xr.w;
    }

    acc0.x += acc1.x; acc0.y += acc1.y; acc0.z += acc1.z; acc0.w += acc1.w;
    acc0.x += __shfl_xor(acc0.x, 32);
    acc0.y += __shfl_xor(acc0.y, 32);
    acc0.z += __shfl_xor(acc0.z, 32);
    acc0.w += __shfl_xor(acc0.w, 32);

    if (g == 0) {
        float4 bb = reinterpret_cast<const float4*>(bias)[f4];
        float4 r;
        r.x = fmaxf(acc0.x + bb.x, 0.f);
        r.y = fmaxf(acc0.y + bb.y, 0.f);
        r.z = fmaxf(acc0.z + bb.z, 0.f);
        r.w = fmaxf(acc0.w + bb.w, 0.f);
        reinterpret_cast<float4*>(&out[(size_t)node * NH])[f4] = r;
    }
}

// One WAVE per node. 8 groups of 8 lanes x float4 (8 x 16B = full 128B row)
// -> 8 independent gathers in flight per wave. Fused bias, no relu.
__global__ __launch_bounds__(256) void agg_nc_kernel(const float* __restrict__ support,
                                                     const int* __restrict__ rowptr,
                                                     const int2* __restrict__ pedge,
                                                     const float* __restrict__ bias,
                                                     float* __restrict__ out) {
    const int wid = threadIdx.x >> 6;
    const int lane = threadIdx.x & 63;
    const int g = lane >> 3;
    const int f4 = lane & 7;
    const int node = blockIdx.x * 4 + wid;
    const int beg = rowptr[node];
    const int end = rowptr[node + 1];

    float4 acc = make_float4(0.f, 0.f, 0.f, 0.f);
    for (int e = beg + g; e < end; e += 8) {
        int2 ed = pedge[e];
        float4 xr = reinterpret_cast<const float4*>(&support[(size_t)ed.x * NC])[f4];
        float v = __int_as_float(ed.y);
        acc.x += v * xr.x; acc.y += v * xr.y; acc.z += v * xr.z; acc.w += v * xr.w;
    }
#pragma unroll
    for (int d = 8; d < 64; d <<= 1) {
        acc.x += __shfl_xor(acc.x, d);
        acc.y += __shfl_xor(acc.y, d);
        acc.z += __shfl_xor(acc.z, d);
        acc.w += __shfl_xor(acc.w, d);
    }
    if (lane < 8) {
        float4 bb = reinterpret_cast<const float4*>(bias)[f4];
        float4 r;
        r.x = acc.x + bb.x; r.y = acc.y + bb.y; r.z = acc.z + bb.z; r.w = acc.w + bb.w;
        reinterpret_cast<float4*>(&out[(size_t)node * NC])[f4] = r;
    }
}

// ---------------- launch ----------------

extern "C" void kernel_launch(void* const* d_in, const int* in_sizes, int n_in,
                              void* d_out, int out_size, void* d_ws, size_t ws_size,
                              hipStream_t stream) {
    const float* x = (const float*)d_in[0];
    const int* esrc = (const int*)d_in[1];
    const int* edst = (const int*)d_in[2];
    const float* eval_ = (const float*)d_in[3];
    const float* W1 = (const float*)d_in[4];
    const float* b1 = (const float*)d_in[5];
    const float* W2 = (const float*)d_in[6];
    const float* b2 = (const float*)d_in[7];
    float* out = (float*)d_out;

    // workspace layout (all >=16B-aligned)
    char* ws = (char*)d_ws;
    float* support1 = (float*)(ws + 0);                 // 51,200,000 B (reused as support2)
    float* h = (float*)(ws + 51200000);                 // 51,200,000 B
    int* rowptr = (int*)(ws + 102400000);               // 400,004 B (padded)
    int* cursor = (int*)(ws + 102800128);               // 400,000 B
    int2* pedge = (int2*)(ws + 103200128);              // 12,800,000 B
    int* chunkSums = (int*)(ws + 116000128);            // 512 B
    int* chunkOffs = (int*)(ws + 116000640);            // 512 B
    unsigned short* w1h = (unsigned short*)(ws + 116001152);  // 65,536 B
    unsigned short* w1l = (unsigned short*)(ws + 116066688);  // 65,536 B
    unsigned short* w2h = (unsigned short*)(ws + 116132224);  // 8,192 B
    unsigned short* w2l = (unsigned short*)(ws + 116140416);  // 8,192 B
    float* support2 = support1;
    (void)ws_size; (void)in_sizes; (void)n_in; (void)out_size;

    // ---- weight conversion (independent of CSR build) ----
    wconv_kernel<<<(NF * NH + NH * NC + 255) / 256, 256, 0, stream>>>(W1, W2, w1h, w1l, w2h, w2l);

    // ---- CSR build ----
    int* counts = cursor;
    zero_int_kernel<<<(NN + 255) / 256, 256, 0, stream>>>(counts, NN);
    hist_kernel<<<(NE + 255) / 256, 256, 0, stream>>>(edst, counts, NE);
    chunk_reduce_kernel<<<SCAN_NCH, 256, 0, stream>>>(counts, chunkSums, NN);
    scan_chunks_kernel<<<1, 64, 0, stream>>>(chunkSums, chunkOffs, rowptr, SCAN_NCH, NN, NE);
    chunk_scan_kernel<<<SCAN_NCH, 256, 0, stream>>>(counts, chunkOffs, rowptr, cursor, NN);
    scatter_kernel<<<(NE + 255) / 256, 256, 0, stream>>>(esrc, edst, eval_, cursor, pedge, NE);

    // ---- layer 1: support1 = x @ W1 (MFMA bf16-split); h = relu(Agg + b1) ----
    gemm_mfma_kernel<2, 2, 2, 2, NF><<<(NN + 127) / 128, 256, 0, stream>>>(x, w1h, w1l, support1, NN);
    agg_nh_kernel<<<NN / 4, 256, 0, stream>>>(support1, rowptr, pedge, b1, h);

    // ---- layer 2: support2 = h @ W2 (MFMA bf16-split); out = Agg + b2 ----
    gemm_mfma_kernel<2, 1, 2, 1, NH><<<(NN + 127) / 128, 128, 0, stream>>>(h, w2h, w2l, support2, NN);
    agg_nc_kernel<<<NN / 4, 256, 0, stream>>>(support2, rowptr, pedge, b2, out);
}

// Round 7
// 511.552 us; speedup vs baseline: 1.3930x; 1.0953x over previous
//
#include <hip/hip_runtime.h>
#include <hip/hip_bf16.h>
#include <cstddef>
#include <cstdint>

// ---------------- problem constants ----------------
constexpr int NN = 100000;   // nodes
constexpr int NE = 1600000;  // edges
constexpr int NF = 256;      // in features
constexpr int NH = 128;      // hidden
constexpr int NC = 32;       // classes

typedef __attribute__((ext_vector_type(8))) short short8v;   // 8 bf16 = 4 VGPR
typedef __attribute__((ext_vector_type(16))) float f32x16;   // MFMA 32x32 acc

// round-to-nearest-even fp32 -> bf16 split: a ~= hi + lo, |err| <~ 2^-17 |a|
__device__ inline void bf16split(float a, unsigned short& h, unsigned short& l) {
    unsigned int ab = __float_as_uint(a);
    unsigned int r = ab + 0x7FFFu + ((ab >> 16) & 1u);
    h = (unsigned short)(r >> 16);
    float hf = __uint_as_float((unsigned int)h << 16);
    float res = a - hf;
    unsigned int rb = __float_as_uint(res);
    unsigned int r2 = rb + 0x7FFFu + ((rb >> 16) & 1u);
    l = (unsigned short)(r2 >> 16);
}

// ---------------- CSR build ----------------

__global__ __launch_bounds__(256) void zero_int_kernel(int* __restrict__ p, int n) {
    int i = blockIdx.x * 256 + threadIdx.x;
    if (i < n) p[i] = 0;
}

// hist also emits per-edge rank within its destination. The atomic return value
// only feeds a store -> no wave stall (stores are fire-and-forget until waitcnt).
__global__ __launch_bounds__(256) void hist_kernel(const int* __restrict__ edst,
                                                   int* __restrict__ counts,
                                                   int* __restrict__ rank, int ne) {
    int i = blockIdx.x * 256 + threadIdx.x;
    if (i < ne) rank[i] = atomicAdd(&counts[edst[i]], 1);
}

constexpr int SCAN_CHUNK = 1024;
constexpr int SCAN_NCH = (NN + SCAN_CHUNK - 1) / SCAN_CHUNK;  // 98

__global__ __launch_bounds__(256) void chunk_reduce_kernel(const int* __restrict__ counts,
                                                           int* __restrict__ chunkSums, int n) {
    __shared__ int sdata[256];
    int tid = threadIdx.x;
    int base = blockIdx.x * SCAN_CHUNK + tid * 4;
    int s = 0;
#pragma unroll
    for (int i = 0; i < 4; ++i)
        if (base + i < n) s += counts[base + i];
    sdata[tid] = s;
    __syncthreads();
    for (int off = 128; off > 0; off >>= 1) {
        if (tid < off) sdata[tid] += sdata[tid + off];
        __syncthreads();
    }
    if (tid == 0) chunkSums[blockIdx.x] = sdata[0];
}

__global__ void scan_chunks_kernel(const int* __restrict__ chunkSums,
                                   int* __restrict__ chunkOffs,
                                   int* __restrict__ rowptr, int nch, int n, int total) {
    if (blockIdx.x == 0 && threadIdx.x == 0) {
        int a = 0;
        for (int i = 0; i < nch; ++i) { int t = chunkSums[i]; chunkOffs[i] = a; a += t; }
        rowptr[n] = total;
    }
}

__global__ __launch_bounds__(256) void chunk_scan_kernel(const int* __restrict__ counts,
                                                         const int* __restrict__ chunkOffs,
                                                         int* __restrict__ rowptr, int n) {
    int tid = threadIdx.x;
    int b = blockIdx.x;
    int base = b * SCAN_CHUNK + tid * 4;
    int v[4];
    int s = 0;
#pragma unroll
    for (int i = 0; i < 4; ++i) {
        v[i] = (base + i < n) ? counts[base + i] : 0;
        s += v[i];
    }
    int lane = tid & 63, wid = tid >> 6;
    int x = s;
#pragma unroll
    for (int d = 1; d < 64; d <<= 1) {
        int y = __shfl_up(x, d);
        if (lane >= d) x += y;
    }
    __shared__ int wtot[4];
    if (lane == 63) wtot[wid] = x;
    __syncthreads();
    int woff = 0;
    for (int w = 0; w < wid; ++w) woff += wtot[w];
    int excl = chunkOffs[b] + woff + (x - s);
#pragma unroll
    for (int i = 0; i < 4; ++i) {
        if (base + i < n) rowptr[base + i] = excl;
        excl += v[i];
    }
}

// XCD-pinned, atomic-free scatter. Grid = NSLICES x 8; block b owns dst range
// [(b&7)*12500, +12500) so each 1.6MB pedge range is dirtied by one XCD's L2
// (round-robin block->XCD dispatch): lines merge fully before writeback.
// Correct regardless of the actual block->XCD mapping (perf heuristic only).
constexpr int SL_EDGES = 4096;
constexpr int NSLICES = (NE + SL_EDGES - 1) / SL_EDGES;  // 391
constexpr int DPX = NN / 8;                              // 12500 dsts per XCD range

__global__ __launch_bounds__(256) void scatter_kernel(const int* __restrict__ esrc,
                                                      const int* __restrict__ edst,
                                                      const float* __restrict__ eval_,
                                                      const int* __restrict__ rowptr,
                                                      const int* __restrict__ rank,
                                                      int2* __restrict__ pedge, int ne) {
    const int xcd = blockIdx.x & 7;
    const int slice = blockIdx.x >> 3;
    const int lo = xcd * DPX;
    const int hi = lo + DPX;
    const int base = slice * SL_EDGES;
#pragma unroll
    for (int k = 0; k < SL_EDGES; k += 256) {
        int i = base + k + threadIdx.x;
        if (i < ne) {
            int d = edst[i];
            if (d >= lo && d < hi) {
                int pos = rowptr[d] + rank[i];
                pedge[pos] = make_int2(esrc[i], __float_as_int(eval_[i]));
            }
        }
    }
}

// ---------------- weight transpose + bf16 split (once per launch, tiny) ----------------
__global__ __launch_bounds__(256) void wconv_kernel(const float* __restrict__ W1,
                                                    const float* __restrict__ W2,
                                                    unsigned short* __restrict__ w1h,
                                                    unsigned short* __restrict__ w1l,
                                                    unsigned short* __restrict__ w2h,
                                                    unsigned short* __restrict__ w2l) {
    int i = blockIdx.x * 256 + threadIdx.x;
    if (i < NF * NH) {
        int k = i / NH, n = i % NH;
        unsigned short h, l;
        bf16split(W1[i], h, l);
        w1h[n * NF + k] = h;
        w1l[n * NF + k] = l;
    } else if (i < NF * NH + NH * NC) {
        int j = i - NF * NH;
        int k = j / NC, n = j % NC;
        unsigned short h, l;
        bf16split(W2[j], h, l);
        w2h[n * NH + k] = h;
        w2l[n * NH + k] = l;
    }
}

// ---------------- bf16-split MFMA GEMM: C[M,N] = A[M,K] @ B[K,N] ----------------
template <int WM, int WN, int RT, int CT, int K>
__global__ __launch_bounds__(WM * WN * 64) void gemm_mfma_kernel(
    const float* __restrict__ A,
    const unsigned short* __restrict__ Bth,
    const unsigned short* __restrict__ Btl,
    float* __restrict__ C, int M) {
    constexpr int NTHREADS = WM * WN * 64;
    constexpr int BM = WM * RT * 32;
    constexpr int BN = WN * CT * 32;
    constexpr int ATILES = WM * RT;
    constexpr int BTILES = WN * CT;
    constexpr int A_HI = 0;
    constexpr int A_LO = ATILES * 1024;
    constexpr int B_HI = 2 * ATILES * 1024;
    constexpr int B_LO = B_HI + BTILES * 1024;
    __shared__ __align__(16) unsigned char smem[B_LO + BTILES * 1024];

    const int tid = threadIdx.x;
    const int lane = tid & 63;
    const int w = tid >> 6;
    const int wm = w % WM;
    const int wn = w / WM;
    const int m0 = blockIdx.x * BM;

    f32x16 acc[RT][CT];
#pragma unroll
    for (int r = 0; r < RT; ++r)
#pragma unroll
        for (int c = 0; c < CT; ++c) acc[r][c] = (f32x16)(0.0f);

    for (int k0 = 0; k0 < K; k0 += 16) {
        // ---- stage A: BM x 16 fp32 -> bf16 hi/lo, fragment-ordered ----
#pragma unroll
        for (int idx = tid; idx < BM * 4; idx += NTHREADS) {
            int row = idx >> 2, kq = idx & 3;
            int grow = m0 + row;
            float4 v = make_float4(0.f, 0.f, 0.f, 0.f);
            if (grow < M) v = *reinterpret_cast<const float4*>(&A[(size_t)grow * K + k0 + kq * 4]);
            unsigned short h0, h1, h2, h3, l0, l1, l2, l3;
            bf16split(v.x, h0, l0);
            bf16split(v.y, h1, l1);
            bf16split(v.z, h2, l2);
            bf16split(v.w, h3, l3);
            uint2 hh, ll;
            hh.x = (unsigned)h0 | ((unsigned)h1 << 16);
            hh.y = (unsigned)h2 | ((unsigned)h3 << 16);
            ll.x = (unsigned)l0 | ((unsigned)l1 << 16);
            ll.y = (unsigned)l2 | ((unsigned)l3 << 16);
            int off = (row >> 5) * 1024 + (kq >> 1) * 512 + (row & 31) * 16 + (kq & 1) * 8;
            *reinterpret_cast<uint2*>(&smem[A_HI + off]) = hh;
            *reinterpret_cast<uint2*>(&smem[A_LO + off]) = ll;
        }
        // ---- stage B: BN x 16 bf16 hi/lo (already split), fragment-ordered ----
#pragma unroll
        for (int idx = tid; idx < BN * 2; idx += NTHREADS) {
            int n = idx >> 1, kg = idx & 1;
            uint4 vh = *reinterpret_cast<const uint4*>(&Bth[(size_t)n * K + k0 + kg * 8]);
            uint4 vl = *reinterpret_cast<const uint4*>(&Btl[(size_t)n * K + k0 + kg * 8]);
            int off = (n >> 5) * 1024 + kg * 512 + (n & 31) * 16;
            *reinterpret_cast<uint4*>(&smem[B_HI + off]) = vh;
            *reinterpret_cast<uint4*>(&smem[B_LO + off]) = vl;
        }
        __syncthreads();

        short8v ah[RT], al[RT], bh[CT], bl[CT];
#pragma unroll
        for (int r = 0; r < RT; ++r) {
            int off = (wm * RT + r) * 1024 + lane * 16;
            ah[r] = *reinterpret_cast<const short8v*>(&smem[A_HI + off]);
            al[r] = *reinterpret_cast<const short8v*>(&smem[A_LO + off]);
        }
#pragma unroll
        for (int c = 0; c < CT; ++c) {
            int off = (wn * CT + c) * 1024 + lane * 16;
            bh[c] = *reinterpret_cast<const short8v*>(&smem[B_HI + off]);
            bl[c] = *reinterpret_cast<const short8v*>(&smem[B_LO + off]);
        }
#pragma unroll
        for (int r = 0; r < RT; ++r)
#pragma unroll
            for (int c = 0; c < CT; ++c) {
                acc[r][c] = __builtin_amdgcn_mfma_f32_32x32x16_bf16(ah[r], bh[c], acc[r][c], 0, 0, 0);
                acc[r][c] = __builtin_amdgcn_mfma_f32_32x32x16_bf16(al[r], bh[c], acc[r][c], 0, 0, 0);
                acc[r][c] = __builtin_amdgcn_mfma_f32_32x32x16_bf16(ah[r], bl[c], acc[r][c], 0, 0, 0);
            }
        __syncthreads();
    }

    // ---- epilogue: C[row][col], col=lane&31, row=(reg&3)+8*(reg>>2)+4*(lane>>5) ----
    const int lo32 = lane & 31;
    const int hi32 = lane >> 5;
#pragma unroll
    for (int r = 0; r < RT; ++r)
#pragma unroll
        for (int c = 0; c < CT; ++c) {
            int rowbase = m0 + (wm * RT + r) * 32 + 4 * hi32;
            int col = (wn * CT + c) * 32 + lo32;
#pragma unroll
            for (int g = 0; g < 4; ++g)
#pragma unroll
                for (int q = 0; q < 4; ++q) {
                    int row = rowbase + 8 * g + q;
                    if (row < M) C[(size_t)row * BN + col] = acc[r][c][g * 4 + q];
                }
        }
}

// ---------------- aggregation (SpMM via CSR) ----------------

// One WAVE per node. 2 half-waves x float4/lane (32 lanes x 16B = full 512B row),
// 4-deep unroll -> 8 independent gathers in flight per wave. Fused bias+relu.
__global__ __launch_bounds__(256) void agg_nh_kernel(const float* __restrict__ support,
                                                     const int* __restrict__ rowptr,
                                                     const int2* __restrict__ pedge,
                                                     const float* __restrict__ bias,
                                                     float* __restrict__ out) {
    const int wid = threadIdx.x >> 6;
    const int lane = threadIdx.x & 63;
    const int g = lane >> 5;
    const int f4 = lane & 31;
    const int node = blockIdx.x * 4 + wid;
    const int beg = rowptr[node];
    const int end = rowptr[node + 1];

    float4 a0 = make_float4(0.f, 0.f, 0.f, 0.f);
    float4 a1 = make_float4(0.f, 0.f, 0.f, 0.f);
    float4 a2 = make_float4(0.f, 0.f, 0.f, 0.f);
    float4 a3 = make_float4(0.f, 0.f, 0.f, 0.f);

    int e = beg + g;
    for (; e + 6 < end; e += 8) {   // this half-wave: edges e, e+2, e+4, e+6
        int2 e0 = pedge[e];
        int2 e1 = pedge[e + 2];
        int2 e2 = pedge[e + 4];
        int2 e3 = pedge[e + 6];
        float4 x0 = reinterpret_cast<const float4*>(&support[(size_t)e0.x * NH])[f4];
        float4 x1 = reinterpret_cast<const float4*>(&support[(size_t)e1.x * NH])[f4];
        float4 x2 = reinterpret_cast<const float4*>(&support[(size_t)e2.x * NH])[f4];
        float4 x3 = reinterpret_cast<const float4*>(&support[(size_t)e3.x * NH])[f4];
        float v0 = __int_as_float(e0.y), v1 = __int_as_float(e1.y);
        float v2 = __int_as_float(e2.y), v3 = __int_as_float(e3.y);
        a0.x += v0 * x0.x; a0.y += v0 * x0.y; a0.z += v0 * x0.z; a0.w += v0 * x0.w;
        a1.x += v1 * x1.x; a1.y += v1 * x1.y; a1.z += v1 * x1.z; a1.w += v1 * x1.w;
        a2.x += v2 * x2.x; a2.y += v2 * x2.y; a2.z += v2 * x2.z; a2.w += v2 * x2.w;
        a3.x += v3 * x3.x; a3.y += v3 * x3.y; a3.z += v3 * x3.z; a3.w += v3 * x3.w;
    }
    for (; e < end; e += 2) {
        int2 ed = pedge[e];
        float4 xr = reinterpret_cast<const float4*>(&support[(size_t)ed.x * NH])[f4];
        float v = __int_as_float(ed.y);
        a0.x += v * xr.x; a0.y += v * xr.y; a0.z += v * xr.z; a0.w += v * xr.w;
    }

    a0.x += a1.x + a2.x + a3.x;
    a0.y += a1.y + a2.y + a3.y;
    a0.z += a1.z + a2.z + a3.z;
    a0.w += a1.w + a2.w + a3.w;
    a0.x += __shfl_xor(a0.x, 32);
    a0.y += __shfl_xor(a0.y, 32);
    a0.z += __shfl_xor(a0.z, 32);
    a0.w += __shfl_xor(a0.w, 32);

    if (g == 0) {
        float4 bb = reinterpret_cast<const float4*>(bias)[f4];
        float4 r;
        r.x = fmaxf(a0.x + bb.x, 0.f);
        r.y = fmaxf(a0.y + bb.y, 0.f);
        r.z = fmaxf(a0.z + bb.z, 0.f);
        r.w = fmaxf(a0.w + bb.w, 0.f);
        reinterpret_cast<float4*>(&out[(size_t)node * NH])[f4] = r;
    }
}

// One WAVE per node. 8 groups of 8 lanes x float4 (8 x 16B = full 128B row)
// -> 8 independent gathers in flight per wave. Fused bias, no relu.
__global__ __launch_bounds__(256) void agg_nc_kernel(const float* __restrict__ support,
                                                     const int* __restrict__ rowptr,
                                                     const int2* __restrict__ pedge,
                                                     const float* __restrict__ bias,
                                                     float* __restrict__ out) {
    const int wid = threadIdx.x >> 6;
    const int lane = threadIdx.x & 63;
    const int g = lane >> 3;
    const int f4 = lane & 7;
    const int node = blockIdx.x * 4 + wid;
    const int beg = rowptr[node];
    const int end = rowptr[node + 1];

    float4 acc = make_float4(0.f, 0.f, 0.f, 0.f);
    for (int e = beg + g; e < end; e += 8) {
        int2 ed = pedge[e];
        float4 xr = reinterpret_cast<const float4*>(&support[(size_t)ed.x * NC])[f4];
        float v = __int_as_float(ed.y);
        acc.x += v * xr.x; acc.y += v * xr.y; acc.z += v * xr.z; acc.w += v * xr.w;
    }
#pragma unroll
    for (int d = 8; d < 64; d <<= 1) {
        acc.x += __shfl_xor(acc.x, d);
        acc.y += __shfl_xor(acc.y, d);
        acc.z += __shfl_xor(acc.z, d);
        acc.w += __shfl_xor(acc.w, d);
    }
    if (lane < 8) {
        float4 bb = reinterpret_cast<const float4*>(bias)[f4];
        float4 r;
        r.x = acc.x + bb.x; r.y = acc.y + bb.y; r.z = acc.z + bb.z; r.w = acc.w + bb.w;
        reinterpret_cast<float4*>(&out[(size_t)node * NC])[f4] = r;
    }
}

// ---------------- launch ----------------

extern "C" void kernel_launch(void* const* d_in, const int* in_sizes, int n_in,
                              void* d_out, int out_size, void* d_ws, size_t ws_size,
                              hipStream_t stream) {
    const float* x = (const float*)d_in[0];
    const int* esrc = (const int*)d_in[1];
    const int* edst = (const int*)d_in[2];
    const float* eval_ = (const float*)d_in[3];
    const float* W1 = (const float*)d_in[4];
    const float* b1 = (const float*)d_in[5];
    const float* W2 = (const float*)d_in[6];
    const float* b2 = (const float*)d_in[7];
    float* out = (float*)d_out;

    // workspace layout (all >=16B-aligned)
    char* ws = (char*)d_ws;
    float* support1 = (float*)(ws + 0);                 // 51,200,000 B (reused as support2)
    int* rank = (int*)(ws + 0);                         // 6,400,000 B — ALIASES support1:
                                                        //   written by hist, read by scatter,
                                                        //   dead before gemm1 writes support1
    float* h = (float*)(ws + 51200000);                 // 51,200,000 B
    int* rowptr = (int*)(ws + 102400000);               // 400,004 B (padded)
    int* counts = (int*)(ws + 102800128);               // 400,000 B
    int2* pedge = (int2*)(ws + 103200128);              // 12,800,000 B
    int* chunkSums = (int*)(ws + 116000128);            // 512 B
    int* chunkOffs = (int*)(ws + 116000640);            // 512 B
    unsigned short* w1h = (unsigned short*)(ws + 116001152);  // 65,536 B
    unsigned short* w1l = (unsigned short*)(ws + 116066688);  // 65,536 B
    unsigned short* w2h = (unsigned short*)(ws + 116132224);  // 8,192 B
    unsigned short* w2l = (unsigned short*)(ws + 116140416);  // 8,192 B
    float* support2 = support1;
    (void)ws_size; (void)in_sizes; (void)n_in; (void)out_size;

    // ---- weight conversion (independent of CSR build) ----
    wconv_kernel<<<(NF * NH + NH * NC + 255) / 256, 256, 0, stream>>>(W1, W2, w1h, w1l, w2h, w2l);

    // ---- CSR build: hist(+rank) -> scan -> XCD-pinned atomic-free scatter ----
    zero_int_kernel<<<(NN + 255) / 256, 256, 0, stream>>>(counts, NN);
    hist_kernel<<<(NE + 255) / 256, 256, 0, stream>>>(edst, counts, rank, NE);
    chunk_reduce_kernel<<<SCAN_NCH, 256, 0, stream>>>(counts, chunkSums, NN);
    scan_chunks_kernel<<<1, 64, 0, stream>>>(chunkSums, chunkOffs, rowptr, SCAN_NCH, NN, NE);
    chunk_scan_kernel<<<SCAN_NCH, 256, 0, stream>>>(counts, chunkOffs, rowptr, NN);
    scatter_kernel<<<NSLICES * 8, 256, 0, stream>>>(esrc, edst, eval_, rowptr, rank, pedge, NE);

    // ---- layer 1: support1 = x @ W1 (MFMA bf16-split); h = relu(Agg + b1) ----
    gemm_mfma_kernel<2, 2, 2, 2, NF><<<(NN + 127) / 128, 256, 0, stream>>>(x, w1h, w1l, support1, NN);
    agg_nh_kernel<<<NN / 4, 256, 0, stream>>>(support1, rowptr, pedge, b1, h);

    // ---- layer 2: support2 = h @ W2 (MFMA bf16-split); out = Agg + b2 ----
    gemm_mfma_kernel<2, 1, 2, 1, NH><<<(NN + 127) / 128, 128, 0, stream>>>(h, w2h, w2l, support2, NN);
    agg_nc_kernel<<<NN / 4, 256, 0, stream>>>(support2, rowptr, pedge, b2, out);
}

// Round 8
// 479.755 us; speedup vs baseline: 1.4854x; 1.0663x over previous
//
#include <hip/hip_runtime.h>
#include <hip/hip_bf16.h>
#include <cstddef>
#include <cstdint>

// ---------------- problem constants ----------------
constexpr int NN = 100000;   // nodes
constexpr int NE = 1600000;  // edges
constexpr int NF = 256;      // in features
constexpr int NH = 128;      // hidden
constexpr int NC = 32;       // classes

typedef __attribute__((ext_vector_type(8))) short short8v;   // 8 bf16 = 4 VGPR
typedef __attribute__((ext_vector_type(16))) float f32x16;   // MFMA 32x32 acc

// round-to-nearest-even fp32 -> bf16 split: a ~= hi + lo, |err| <~ 2^-17 |a|
__device__ inline void bf16split(float a, unsigned short& h, unsigned short& l) {
    unsigned int ab = __float_as_uint(a);
    unsigned int r = ab + 0x7FFFu + ((ab >> 16) & 1u);
    h = (unsigned short)(r >> 16);
    float hf = __uint_as_float((unsigned int)h << 16);
    float res = a - hf;
    unsigned int rb = __float_as_uint(res);
    unsigned int r2 = rb + 0x7FFFu + ((rb >> 16) & 1u);
    l = (unsigned short)(r2 >> 16);
}

__device__ inline unsigned short f2bf(float a) {  // RNE fp32->bf16
    unsigned int ab = __float_as_uint(a);
    return (unsigned short)((ab + 0x7FFFu + ((ab >> 16) & 1u)) >> 16);
}

// 8 bf16 (uint4) scaled-accumulate into fp32[8]
__device__ inline void fma8(float* a, uint4 q, float v) {
    a[0] = fmaf(v, __uint_as_float(q.x << 16), a[0]);
    a[1] = fmaf(v, __uint_as_float(q.x & 0xFFFF0000u), a[1]);
    a[2] = fmaf(v, __uint_as_float(q.y << 16), a[2]);
    a[3] = fmaf(v, __uint_as_float(q.y & 0xFFFF0000u), a[3]);
    a[4] = fmaf(v, __uint_as_float(q.z << 16), a[4]);
    a[5] = fmaf(v, __uint_as_float(q.z & 0xFFFF0000u), a[5]);
    a[6] = fmaf(v, __uint_as_float(q.w << 16), a[6]);
    a[7] = fmaf(v, __uint_as_float(q.w & 0xFFFF0000u), a[7]);
}

// ---------------- CSR build ----------------

__global__ __launch_bounds__(256) void zero_int_kernel(int* __restrict__ p, int n) {
    int i = blockIdx.x * 256 + threadIdx.x;
    if (i < n) p[i] = 0;
}

// hist also emits per-edge rank within its destination. The atomic return value
// only feeds a store -> no wave stall.
__global__ __launch_bounds__(256) void hist_kernel(const int* __restrict__ edst,
                                                   int* __restrict__ counts,
                                                   int* __restrict__ rank, int ne) {
    int i = blockIdx.x * 256 + threadIdx.x;
    if (i < ne) rank[i] = atomicAdd(&counts[edst[i]], 1);
}

constexpr int SCAN_CHUNK = 1024;
constexpr int SCAN_NCH = (NN + SCAN_CHUNK - 1) / SCAN_CHUNK;  // 98

__global__ __launch_bounds__(256) void chunk_reduce_kernel(const int* __restrict__ counts,
                                                           int* __restrict__ chunkSums, int n) {
    __shared__ int sdata[256];
    int tid = threadIdx.x;
    int base = blockIdx.x * SCAN_CHUNK + tid * 4;
    int s = 0;
#pragma unroll
    for (int i = 0; i < 4; ++i)
        if (base + i < n) s += counts[base + i];
    sdata[tid] = s;
    __syncthreads();
    for (int off = 128; off > 0; off >>= 1) {
        if (tid < off) sdata[tid] += sdata[tid + off];
        __syncthreads();
    }
    if (tid == 0) chunkSums[blockIdx.x] = sdata[0];
}

__global__ void scan_chunks_kernel(const int* __restrict__ chunkSums,
                                   int* __restrict__ chunkOffs,
                                   int* __restrict__ rowptr, int nch, int n, int total) {
    if (blockIdx.x == 0 && threadIdx.x == 0) {
        int a = 0;
        for (int i = 0; i < nch; ++i) { int t = chunkSums[i]; chunkOffs[i] = a; a += t; }
        rowptr[n] = total;
    }
}

__global__ __launch_bounds__(256) void chunk_scan_kernel(const int* __restrict__ counts,
                                                         const int* __restrict__ chunkOffs,
                                                         int* __restrict__ rowptr, int n) {
    int tid = threadIdx.x;
    int b = blockIdx.x;
    int base = b * SCAN_CHUNK + tid * 4;
    int v[4];
    int s = 0;
#pragma unroll
    for (int i = 0; i < 4; ++i) {
        v[i] = (base + i < n) ? counts[base + i] : 0;
        s += v[i];
    }
    int lane = tid & 63, wid = tid >> 6;
    int x = s;
#pragma unroll
    for (int d = 1; d < 64; d <<= 1) {
        int y = __shfl_up(x, d);
        if (lane >= d) x += y;
    }
    __shared__ int wtot[4];
    if (lane == 63) wtot[wid] = x;
    __syncthreads();
    int woff = 0;
    for (int w = 0; w < wid; ++w) woff += wtot[w];
    int excl = chunkOffs[b] + woff + (x - s);
#pragma unroll
    for (int i = 0; i < 4; ++i) {
        if (base + i < n) rowptr[base + i] = excl;
        excl += v[i];
    }
}

// XCD-pinned, atomic-free scatter (proven R7: WRITE_SIZE merge works).
constexpr int SL_EDGES = 4096;
constexpr int NSLICES = (NE + SL_EDGES - 1) / SL_EDGES;  // 391
constexpr int DPX = NN / 8;                              // 12500 dsts per XCD range

__global__ __launch_bounds__(256) void scatter_kernel(const int* __restrict__ esrc,
                                                      const int* __restrict__ edst,
                                                      const float* __restrict__ eval_,
                                                      const int* __restrict__ rowptr,
                                                      const int* __restrict__ rank,
                                                      int2* __restrict__ pedge, int ne) {
    const int xcd = blockIdx.x & 7;
    const int slice = blockIdx.x >> 3;
    const int lo = xcd * DPX;
    const int hi = lo + DPX;
    const int base = slice * SL_EDGES;
#pragma unroll
    for (int k = 0; k < SL_EDGES; k += 256) {
        int i = base + k + threadIdx.x;
        if (i < ne) {
            int d = edst[i];
            if (d >= lo && d < hi) {
                int pos = rowptr[d] + rank[i];
                pedge[pos] = make_int2(esrc[i], __float_as_int(eval_[i]));
            }
        }
    }
}

// ---------------- weight transpose + bf16 split (once per launch, tiny) ----------------
__global__ __launch_bounds__(256) void wconv_kernel(const float* __restrict__ W1,
                                                    const float* __restrict__ W2,
                                                    unsigned short* __restrict__ w1h,
                                                    unsigned short* __restrict__ w1l,
                                                    unsigned short* __restrict__ w2h,
                                                    unsigned short* __restrict__ w2l) {
    int i = blockIdx.x * 256 + threadIdx.x;
    if (i < NF * NH) {
        int k = i / NH, n = i % NH;
        unsigned short h, l;
        bf16split(W1[i], h, l);
        w1h[n * NF + k] = h;
        w1l[n * NF + k] = l;
    } else if (i < NF * NH + NH * NC) {
        int j = i - NF * NH;
        int k = j / NC, n = j % NC;
        unsigned short h, l;
        bf16split(W2[j], h, l);
        w2h[n * NH + k] = h;
        w2l[n * NH + k] = l;
    }
}

// ---------------- gemm1: C_bf16[M,BN] = A_f32[M,K] @ B[K,BN], bf16-split (3 MFMA/tile) ----------------
template <int WM, int WN, int RT, int CT, int K>
__global__ __launch_bounds__(WM * WN * 64) void gemm_mfma_kernel(
    const float* __restrict__ A,
    const unsigned short* __restrict__ Bth,
    const unsigned short* __restrict__ Btl,
    unsigned short* __restrict__ C, int M) {
    constexpr int NTHREADS = WM * WN * 64;
    constexpr int BM = WM * RT * 32;
    constexpr int BN = WN * CT * 32;
    constexpr int ATILES = WM * RT;
    constexpr int BTILES = WN * CT;
    constexpr int A_HI = 0;
    constexpr int A_LO = ATILES * 1024;
    constexpr int B_HI = 2 * ATILES * 1024;
    constexpr int B_LO = B_HI + BTILES * 1024;
    __shared__ __align__(16) unsigned char smem[B_LO + BTILES * 1024];

    const int tid = threadIdx.x;
    const int lane = tid & 63;
    const int w = tid >> 6;
    const int wm = w % WM;
    const int wn = w / WM;
    const int m0 = blockIdx.x * BM;

    f32x16 acc[RT][CT];
#pragma unroll
    for (int r = 0; r < RT; ++r)
#pragma unroll
        for (int c = 0; c < CT; ++c) acc[r][c] = (f32x16)(0.0f);

    for (int k0 = 0; k0 < K; k0 += 16) {
#pragma unroll
        for (int idx = tid; idx < BM * 4; idx += NTHREADS) {
            int row = idx >> 2, kq = idx & 3;
            int grow = m0 + row;
            float4 v = make_float4(0.f, 0.f, 0.f, 0.f);
            if (grow < M) v = *reinterpret_cast<const float4*>(&A[(size_t)grow * K + k0 + kq * 4]);
            unsigned short h0, h1, h2, h3, l0, l1, l2, l3;
            bf16split(v.x, h0, l0);
            bf16split(v.y, h1, l1);
            bf16split(v.z, h2, l2);
            bf16split(v.w, h3, l3);
            uint2 hh, ll;
            hh.x = (unsigned)h0 | ((unsigned)h1 << 16);
            hh.y = (unsigned)h2 | ((unsigned)h3 << 16);
            ll.x = (unsigned)l0 | ((unsigned)l1 << 16);
            ll.y = (unsigned)l2 | ((unsigned)l3 << 16);
            int off = (row >> 5) * 1024 + (kq >> 1) * 512 + (row & 31) * 16 + (kq & 1) * 8;
            *reinterpret_cast<uint2*>(&smem[A_HI + off]) = hh;
            *reinterpret_cast<uint2*>(&smem[A_LO + off]) = ll;
        }
#pragma unroll
        for (int idx = tid; idx < BN * 2; idx += NTHREADS) {
            int n = idx >> 1, kg = idx & 1;
            uint4 vh = *reinterpret_cast<const uint4*>(&Bth[(size_t)n * K + k0 + kg * 8]);
            uint4 vl = *reinterpret_cast<const uint4*>(&Btl[(size_t)n * K + k0 + kg * 8]);
            int off = (n >> 5) * 1024 + kg * 512 + (n & 31) * 16;
            *reinterpret_cast<uint4*>(&smem[B_HI + off]) = vh;
            *reinterpret_cast<uint4*>(&smem[B_LO + off]) = vl;
        }
        __syncthreads();

        short8v ah[RT], al[RT], bh[CT], bl[CT];
#pragma unroll
        for (int r = 0; r < RT; ++r) {
            int off = (wm * RT + r) * 1024 + lane * 16;
            ah[r] = *reinterpret_cast<const short8v*>(&smem[A_HI + off]);
            al[r] = *reinterpret_cast<const short8v*>(&smem[A_LO + off]);
        }
#pragma unroll
        for (int c = 0; c < CT; ++c) {
            int off = (wn * CT + c) * 1024 + lane * 16;
            bh[c] = *reinterpret_cast<const short8v*>(&smem[B_HI + off]);
            bl[c] = *reinterpret_cast<const short8v*>(&smem[B_LO + off]);
        }
#pragma unroll
        for (int r = 0; r < RT; ++r)
#pragma unroll
            for (int c = 0; c < CT; ++c) {
                acc[r][c] = __builtin_amdgcn_mfma_f32_32x32x16_bf16(ah[r], bh[c], acc[r][c], 0, 0, 0);
                acc[r][c] = __builtin_amdgcn_mfma_f32_32x32x16_bf16(al[r], bh[c], acc[r][c], 0, 0, 0);
                acc[r][c] = __builtin_amdgcn_mfma_f32_32x32x16_bf16(ah[r], bl[c], acc[r][c], 0, 0, 0);
            }
        __syncthreads();
    }

    const int lo32 = lane & 31;
    const int hi32 = lane >> 5;
#pragma unroll
    for (int r = 0; r < RT; ++r)
#pragma unroll
        for (int c = 0; c < CT; ++c) {
            int rowbase = m0 + (wm * RT + r) * 32 + 4 * hi32;
            int col = (wn * CT + c) * 32 + lo32;
#pragma unroll
            for (int g = 0; g < 4; ++g)
#pragma unroll
                for (int q = 0; q < 4; ++q) {
                    int row = rowbase + 8 * g + q;
                    if (row < M) C[(size_t)row * BN + col] = f2bf(acc[r][c][g * 4 + q]);
                }
        }
}

// ---------------- gemm2: C_bf16[M,32] = A_bf16[M,128] @ W2; A exact, W2 split (2 MFMA/tile) ----------------
__global__ __launch_bounds__(128) void gemm2_mfma_kernel(const unsigned short* __restrict__ A,
                                                         const unsigned short* __restrict__ Bth,
                                                         const unsigned short* __restrict__ Btl,
                                                         unsigned short* __restrict__ C, int M) {
    constexpr int BM = 128, BN = 32, K = NH;
    constexpr int B_HI = 4096, B_LO = 5120;
    __shared__ __align__(16) unsigned char smem[6144];

    const int tid = threadIdx.x;
    const int lane = tid & 63;
    const int wm = tid >> 6;  // 2 waves: m-split
    const int m0 = blockIdx.x * BM;

    f32x16 acc[2];
    acc[0] = (f32x16)(0.0f);
    acc[1] = (f32x16)(0.0f);

    for (int k0 = 0; k0 < K; k0 += 16) {
#pragma unroll
        for (int i = 0; i < 2; ++i) {
            int idx = tid + i * 128;
            int row = idx >> 1, kg = idx & 1;
            int gr = m0 + row;
            uint4 v = make_uint4(0, 0, 0, 0);
            if (gr < M) v = *reinterpret_cast<const uint4*>(&A[(size_t)gr * K + k0 + kg * 8]);
            int off = (row >> 5) * 1024 + kg * 512 + (row & 31) * 16;
            *reinterpret_cast<uint4*>(&smem[off]) = v;
        }
        if (tid < 64) {
            int n = tid >> 1, kg = tid & 1;
            uint4 vh = *reinterpret_cast<const uint4*>(&Bth[(size_t)n * K + k0 + kg * 8]);
            uint4 vl = *reinterpret_cast<const uint4*>(&Btl[(size_t)n * K + k0 + kg * 8]);
            int off = kg * 512 + n * 16;
            *reinterpret_cast<uint4*>(&smem[B_HI + off]) = vh;
            *reinterpret_cast<uint4*>(&smem[B_LO + off]) = vl;
        }
        __syncthreads();

        short8v a0 = *reinterpret_cast<const short8v*>(&smem[(wm * 2 + 0) * 1024 + lane * 16]);
        short8v a1 = *reinterpret_cast<const short8v*>(&smem[(wm * 2 + 1) * 1024 + lane * 16]);
        short8v bh = *reinterpret_cast<const short8v*>(&smem[B_HI + lane * 16]);
        short8v bl = *reinterpret_cast<const short8v*>(&smem[B_LO + lane * 16]);
        acc[0] = __builtin_amdgcn_mfma_f32_32x32x16_bf16(a0, bh, acc[0], 0, 0, 0);
        acc[0] = __builtin_amdgcn_mfma_f32_32x32x16_bf16(a0, bl, acc[0], 0, 0, 0);
        acc[1] = __builtin_amdgcn_mfma_f32_32x32x16_bf16(a1, bh, acc[1], 0, 0, 0);
        acc[1] = __builtin_amdgcn_mfma_f32_32x32x16_bf16(a1, bl, acc[1], 0, 0, 0);
        __syncthreads();
    }

    const int lo32 = lane & 31;
    const int hi32 = lane >> 5;
#pragma unroll
    for (int r = 0; r < 2; ++r) {
        int rowbase = m0 + (wm * 2 + r) * 32 + 4 * hi32;
#pragma unroll
        for (int g = 0; g < 4; ++g)
#pragma unroll
            for (int q = 0; q < 4; ++q) {
                int row = rowbase + 8 * g + q;
                if (row < M) C[(size_t)row * BN + lo32] = f2bf(acc[r][g * 4 + q]);
            }
    }
}

// ---------------- aggregation (SpMM via CSR, bf16 activations) ----------------

// One WAVE per node. 256B bf16 row = 16 lanes x uint4; 4 edge streams x 4-deep
// unroll = 16 gathers in flight. fp32 accumulate; fused bias+relu; bf16 out.
__global__ __launch_bounds__(256) void agg_nh_kernel(const unsigned short* __restrict__ support,
                                                     const int* __restrict__ rowptr,
                                                     const int2* __restrict__ pedge,
                                                     const float* __restrict__ bias,
                                                     unsigned short* __restrict__ outh) {
    const int wid = threadIdx.x >> 6;
    const int lane = threadIdx.x & 63;
    const int g = lane >> 4;      // 4 edge streams
    const int f = lane & 15;      // 16B chunk within the 256B row
    const int node = blockIdx.x * 4 + wid;
    const int beg = rowptr[node];
    const int end = rowptr[node + 1];

    float a0[8] = {}, a1[8] = {}, a2[8] = {}, a3[8] = {};

    int e = beg + g;
    for (; e + 12 < end; e += 16) {   // this stream: edges e, e+4, e+8, e+12
        int2 e0 = pedge[e];
        int2 e1 = pedge[e + 4];
        int2 e2 = pedge[e + 8];
        int2 e3 = pedge[e + 12];
        uint4 q0 = reinterpret_cast<const uint4*>(&support[(size_t)e0.x * NH])[f];
        uint4 q1 = reinterpret_cast<const uint4*>(&support[(size_t)e1.x * NH])[f];
        uint4 q2 = reinterpret_cast<const uint4*>(&support[(size_t)e2.x * NH])[f];
        uint4 q3 = reinterpret_cast<const uint4*>(&support[(size_t)e3.x * NH])[f];
        fma8(a0, q0, __int_as_float(e0.y));
        fma8(a1, q1, __int_as_float(e1.y));
        fma8(a2, q2, __int_as_float(e2.y));
        fma8(a3, q3, __int_as_float(e3.y));
    }
    for (; e < end; e += 4) {
        int2 ed = pedge[e];
        uint4 q = reinterpret_cast<const uint4*>(&support[(size_t)ed.x * NH])[f];
        fma8(a0, q, __int_as_float(ed.y));
    }

#pragma unroll
    for (int j = 0; j < 8; ++j) {
        a0[j] += a1[j] + a2[j] + a3[j];
        a0[j] += __shfl_xor(a0[j], 16);
        a0[j] += __shfl_xor(a0[j], 32);
    }

    if (g == 0) {
        float4 b0 = reinterpret_cast<const float4*>(bias)[2 * f];
        float4 b1 = reinterpret_cast<const float4*>(bias)[2 * f + 1];
        float r0 = fmaxf(a0[0] + b0.x, 0.f), r1 = fmaxf(a0[1] + b0.y, 0.f);
        float r2 = fmaxf(a0[2] + b0.z, 0.f), r3 = fmaxf(a0[3] + b0.w, 0.f);
        float r4 = fmaxf(a0[4] + b1.x, 0.f), r5 = fmaxf(a0[5] + b1.y, 0.f);
        float r6 = fmaxf(a0[6] + b1.z, 0.f), r7 = fmaxf(a0[7] + b1.w, 0.f);
        uint4 o;
        o.x = (unsigned)f2bf(r0) | ((unsigned)f2bf(r1) << 16);
        o.y = (unsigned)f2bf(r2) | ((unsigned)f2bf(r3) << 16);
        o.z = (unsigned)f2bf(r4) | ((unsigned)f2bf(r5) << 16);
        o.w = (unsigned)f2bf(r6) | ((unsigned)f2bf(r7) << 16);
        reinterpret_cast<uint4*>(&outh[(size_t)node * NH])[f] = o;
    }
}

// One WAVE per node. 64B bf16 row = 4 lanes x uint4; 16 edge streams in flight.
// fp32 accumulate; fused bias; fp32 out (required output dtype).
__global__ __launch_bounds__(256) void agg_nc_kernel(const unsigned short* __restrict__ support,
                                                     const int* __restrict__ rowptr,
                                                     const int2* __restrict__ pedge,
                                                     const float* __restrict__ bias,
                                                     float* __restrict__ out) {
    const int wid = threadIdx.x >> 6;
    const int lane = threadIdx.x & 63;
    const int g = lane >> 2;      // 16 edge streams
    const int f = lane & 3;       // 16B chunk within the 64B row
    const int node = blockIdx.x * 4 + wid;
    const int beg = rowptr[node];
    const int end = rowptr[node + 1];

    float a[8] = {};
    for (int e = beg + g; e < end; e += 16) {
        int2 ed = pedge[e];
        uint4 q = reinterpret_cast<const uint4*>(&support[(size_t)ed.x * NC])[f];
        fma8(a, q, __int_as_float(ed.y));
    }
#pragma unroll
    for (int j = 0; j < 8; ++j) {
        a[j] += __shfl_xor(a[j], 4);
        a[j] += __shfl_xor(a[j], 8);
        a[j] += __shfl_xor(a[j], 16);
        a[j] += __shfl_xor(a[j], 32);
    }
    if (g == 0) {
        float4 b0 = reinterpret_cast<const float4*>(bias)[2 * f];
        float4 b1 = reinterpret_cast<const float4*>(bias)[2 * f + 1];
        float4 w0 = make_float4(a[0] + b0.x, a[1] + b0.y, a[2] + b0.z, a[3] + b0.w);
        float4 w1 = make_float4(a[4] + b1.x, a[5] + b1.y, a[6] + b1.z, a[7] + b1.w);
        reinterpret_cast<float4*>(&out[(size_t)node * NC])[2 * f] = w0;
        reinterpret_cast<float4*>(&out[(size_t)node * NC])[2 * f + 1] = w1;
    }
}

// ---------------- launch ----------------

extern "C" void kernel_launch(void* const* d_in, const int* in_sizes, int n_in,
                              void* d_out, int out_size, void* d_ws, size_t ws_size,
                              hipStream_t stream) {
    const float* x = (const float*)d_in[0];
    const int* esrc = (const int*)d_in[1];
    const int* edst = (const int*)d_in[2];
    const float* eval_ = (const float*)d_in[3];
    const float* W1 = (const float*)d_in[4];
    const float* b1 = (const float*)d_in[5];
    const float* W2 = (const float*)d_in[6];
    const float* b2 = (const float*)d_in[7];
    float* out = (float*)d_out;

    // workspace layout (all 16B-aligned)
    char* ws = (char*)d_ws;
    unsigned short* sup = (unsigned short*)(ws + 0);    // 25,600,000 B bf16 support1 / support2
    int* rank = (int*)(ws + 0);                         // 6,400,000 B — ALIASES sup:
                                                        //   written by hist, read by scatter,
                                                        //   dead before gemm1 writes sup
    unsigned short* hbuf = (unsigned short*)(ws + 25600000);  // 25,600,000 B bf16 h
    int* rowptr = (int*)(ws + 51200000);                // 400,128 B
    int* counts = (int*)(ws + 51600128);                // 400,384 B
    int2* pedge = (int2*)(ws + 52000512);               // 12,800,000 B
    int* chunkSums = (int*)(ws + 64800512);             // 512 B
    int* chunkOffs = (int*)(ws + 64801024);             // 512 B
    unsigned short* w1h = (unsigned short*)(ws + 64801536);  // 65,536 B
    unsigned short* w1l = (unsigned short*)(ws + 64867072);  // 65,536 B
    unsigned short* w2h = (unsigned short*)(ws + 64932608);  // 8,192 B
    unsigned short* w2l = (unsigned short*)(ws + 64940800);  // 8,192 B
    (void)ws_size; (void)in_sizes; (void)n_in; (void)out_size;

    // ---- weight conversion (independent of CSR build) ----
    wconv_kernel<<<(NF * NH + NH * NC + 255) / 256, 256, 0, stream>>>(W1, W2, w1h, w1l, w2h, w2l);

    // ---- CSR build: hist(+rank) -> scan -> XCD-pinned atomic-free scatter ----
    zero_int_kernel<<<(NN + 255) / 256, 256, 0, stream>>>(counts, NN);
    hist_kernel<<<(NE + 255) / 256, 256, 0, stream>>>(edst, counts, rank, NE);
    chunk_reduce_kernel<<<SCAN_NCH, 256, 0, stream>>>(counts, chunkSums, NN);
    scan_chunks_kernel<<<1, 64, 0, stream>>>(chunkSums, chunkOffs, rowptr, SCAN_NCH, NN, NE);
    chunk_scan_kernel<<<SCAN_NCH, 256, 0, stream>>>(counts, chunkOffs, rowptr, NN);
    scatter_kernel<<<NSLICES * 8, 256, 0, stream>>>(esrc, edst, eval_, rowptr, rank, pedge, NE);

    // ---- layer 1: sup = bf16(x @ W1); h = bf16(relu(Agg(sup) + b1)) ----
    gemm_mfma_kernel<2, 2, 2, 2, NF><<<(NN + 127) / 128, 256, 0, stream>>>(x, w1h, w1l, sup, NN);
    agg_nh_kernel<<<NN / 4, 256, 0, stream>>>(sup, rowptr, pedge, b1, hbuf);

    // ---- layer 2: sup = bf16(h @ W2); out = Agg(sup) + b2 (fp32) ----
    gemm2_mfma_kernel<<<(NN + 127) / 128, 128, 0, stream>>>(hbuf, w2h, w2l, sup, NN);
    agg_nc_kernel<<<NN / 4, 256, 0, stream>>>(sup, rowptr, pedge, b2, out);
}

// Round 9
// 466.334 us; speedup vs baseline: 1.5281x; 1.0288x over previous
//
#include <hip/hip_runtime.h>
#include <hip/hip_bf16.h>
#include <cstddef>
#include <cstdint>

// ---------------- problem constants ----------------
constexpr int NN = 100000;   // nodes
constexpr int NE = 1600000;  // edges
constexpr int NF = 256;      // in features
constexpr int NH = 128;      // hidden
constexpr int NC = 32;       // classes

typedef __attribute__((ext_vector_type(8))) short short8v;   // 8 bf16 = 4 VGPR
typedef __attribute__((ext_vector_type(16))) float f32x16;   // MFMA 32x32 acc
typedef __attribute__((ext_vector_type(2))) float v2f;       // packed fp32 pair (v_pk_fma_f32)

// one-instruction packed RNE fp32->bf16x2 (no builtin on gfx950; T12/m240)
__device__ inline unsigned int cvtpk_bf16(float lo, float hi) {
    unsigned int r;
    asm("v_cvt_pk_bf16_f32 %0, %1, %2" : "=v"(r) : "v"(lo), "v"(hi));
    return r;
}

// round-to-nearest-even fp32 -> bf16 split (scalar; used in tiny wconv only)
__device__ inline void bf16split(float a, unsigned short& h, unsigned short& l) {
    unsigned int ab = __float_as_uint(a);
    unsigned int r = ab + 0x7FFFu + ((ab >> 16) & 1u);
    h = (unsigned short)(r >> 16);
    float hf = __uint_as_float((unsigned int)h << 16);
    float res = a - hf;
    unsigned int rb = __float_as_uint(res);
    unsigned int r2 = rb + 0x7FFFu + ((rb >> 16) & 1u);
    l = (unsigned short)(r2 >> 16);
}

__device__ inline unsigned short f2bf(float a) {  // RNE fp32->bf16
    unsigned int ab = __float_as_uint(a);
    return (unsigned short)((ab + 0x7FFFu + ((ab >> 16) & 1u)) >> 16);
}

// 8 bf16 (uint4) scaled-accumulate into 4x v2f via packed FMA
__device__ inline void fma8pk(v2f* a, uint4 q, v2f v) {
    v2f p0, p1, p2, p3;
    p0.x = __uint_as_float(q.x << 16); p0.y = __uint_as_float(q.x & 0xFFFF0000u);
    p1.x = __uint_as_float(q.y << 16); p1.y = __uint_as_float(q.y & 0xFFFF0000u);
    p2.x = __uint_as_float(q.z << 16); p2.y = __uint_as_float(q.z & 0xFFFF0000u);
    p3.x = __uint_as_float(q.w << 16); p3.y = __uint_as_float(q.w & 0xFFFF0000u);
    a[0] = p0 * v + a[0];   // -ffp-contract=fast -> v_pk_fma_f32
    a[1] = p1 * v + a[1];
    a[2] = p2 * v + a[2];
    a[3] = p3 * v + a[3];
}

// ---------------- CSR build ----------------

__global__ __launch_bounds__(256) void zero_int_kernel(int* __restrict__ p, int n) {
    int i = blockIdx.x * 256 + threadIdx.x;
    if (i < n) p[i] = 0;
}

// hist also emits per-edge rank within its destination. The atomic return value
// only feeds a store -> no wave stall.
__global__ __launch_bounds__(256) void hist_kernel(const int* __restrict__ edst,
                                                   int* __restrict__ counts,
                                                   int* __restrict__ rank, int ne) {
    int i = blockIdx.x * 256 + threadIdx.x;
    if (i < ne) rank[i] = atomicAdd(&counts[edst[i]], 1);
}

constexpr int SCAN_CHUNK = 1024;
constexpr int SCAN_NCH = (NN + SCAN_CHUNK - 1) / SCAN_CHUNK;  // 98

__global__ __launch_bounds__(256) void chunk_reduce_kernel(const int* __restrict__ counts,
                                                           int* __restrict__ chunkSums, int n) {
    __shared__ int sdata[256];
    int tid = threadIdx.x;
    int base = blockIdx.x * SCAN_CHUNK + tid * 4;
    int s = 0;
#pragma unroll
    for (int i = 0; i < 4; ++i)
        if (base + i < n) s += counts[base + i];
    sdata[tid] = s;
    __syncthreads();
    for (int off = 128; off > 0; off >>= 1) {
        if (tid < off) sdata[tid] += sdata[tid + off];
        __syncthreads();
    }
    if (tid == 0) chunkSums[blockIdx.x] = sdata[0];
}

__global__ void scan_chunks_kernel(const int* __restrict__ chunkSums,
                                   int* __restrict__ chunkOffs,
                                   int* __restrict__ rowptr, int nch, int n, int total) {
    if (blockIdx.x == 0 && threadIdx.x == 0) {
        int a = 0;
        for (int i = 0; i < nch; ++i) { int t = chunkSums[i]; chunkOffs[i] = a; a += t; }
        rowptr[n] = total;
    }
}

__global__ __launch_bounds__(256) void chunk_scan_kernel(const int* __restrict__ counts,
                                                         const int* __restrict__ chunkOffs,
                                                         int* __restrict__ rowptr, int n) {
    int tid = threadIdx.x;
    int b = blockIdx.x;
    int base = b * SCAN_CHUNK + tid * 4;
    int v[4];
    int s = 0;
#pragma unroll
    for (int i = 0; i < 4; ++i) {
        v[i] = (base + i < n) ? counts[base + i] : 0;
        s += v[i];
    }
    int lane = tid & 63, wid = tid >> 6;
    int x = s;
#pragma unroll
    for (int d = 1; d < 64; d <<= 1) {
        int y = __shfl_up(x, d);
        if (lane >= d) x += y;
    }
    __shared__ int wtot[4];
    if (lane == 63) wtot[wid] = x;
    __syncthreads();
    int woff = 0;
    for (int w = 0; w < wid; ++w) woff += wtot[w];
    int excl = chunkOffs[b] + woff + (x - s);
#pragma unroll
    for (int i = 0; i < 4; ++i) {
        if (base + i < n) rowptr[base + i] = excl;
        excl += v[i];
    }
}

// XCD-pinned, atomic-free scatter (proven R7: WRITE_SIZE merge works).
constexpr int SL_EDGES = 4096;
constexpr int NSLICES = (NE + SL_EDGES - 1) / SL_EDGES;  // 391
constexpr int DPX = NN / 8;                              // 12500 dsts per XCD range

__global__ __launch_bounds__(256) void scatter_kernel(const int* __restrict__ esrc,
                                                      const int* __restrict__ edst,
                                                      const float* __restrict__ eval_,
                                                      const int* __restrict__ rowptr,
                                                      const int* __restrict__ rank,
                                                      int2* __restrict__ pedge, int ne) {
    const int xcd = blockIdx.x & 7;
    const int slice = blockIdx.x >> 3;
    const int lo = xcd * DPX;
    const int hi = lo + DPX;
    const int base = slice * SL_EDGES;
#pragma unroll
    for (int k = 0; k < SL_EDGES; k += 256) {
        int i = base + k + threadIdx.x;
        if (i < ne) {
            int d = edst[i];
            if (d >= lo && d < hi) {
                int pos = rowptr[d] + rank[i];
                pedge[pos] = make_int2(esrc[i], __float_as_int(eval_[i]));
            }
        }
    }
}

// ---------------- weight transpose + bf16 split (once per launch, tiny) ----------------
__global__ __launch_bounds__(256) void wconv_kernel(const float* __restrict__ W1,
                                                    const float* __restrict__ W2,
                                                    unsigned short* __restrict__ w1h,
                                                    unsigned short* __restrict__ w1l,
                                                    unsigned short* __restrict__ w2h,
                                                    unsigned short* __restrict__ w2l) {
    int i = blockIdx.x * 256 + threadIdx.x;
    if (i < NF * NH) {
        int k = i / NH, n = i % NH;
        unsigned short h, l;
        bf16split(W1[i], h, l);
        w1h[n * NF + k] = h;
        w1l[n * NF + k] = l;
    } else if (i < NF * NH + NH * NC) {
        int j = i - NF * NH;
        int k = j / NC, n = j % NC;
        unsigned short h, l;
        bf16split(W2[j], h, l);
        w2h[n * NH + k] = h;
        w2l[n * NH + k] = l;
    }
}

// ---------------- gemm1: C_bf16[M,BN] = A_f32[M,K] @ B[K,BN], bf16-split (3 MFMA/tile) ----------------
template <int WM, int WN, int RT, int CT, int K>
__global__ __launch_bounds__(WM * WN * 64) void gemm_mfma_kernel(
    const float* __restrict__ A,
    const unsigned short* __restrict__ Bth,
    const unsigned short* __restrict__ Btl,
    unsigned short* __restrict__ C, int M) {
    constexpr int NTHREADS = WM * WN * 64;
    constexpr int BM = WM * RT * 32;
    constexpr int BN = WN * CT * 32;
    constexpr int ATILES = WM * RT;
    constexpr int BTILES = WN * CT;
    constexpr int A_HI = 0;
    constexpr int A_LO = ATILES * 1024;
    constexpr int B_HI = 2 * ATILES * 1024;
    constexpr int B_LO = B_HI + BTILES * 1024;
    __shared__ __align__(16) unsigned char smem[B_LO + BTILES * 1024];

    const int tid = threadIdx.x;
    const int lane = tid & 63;
    const int w = tid >> 6;
    const int wm = w % WM;
    const int wn = w / WM;
    const int m0 = blockIdx.x * BM;

    f32x16 acc[RT][CT];
#pragma unroll
    for (int r = 0; r < RT; ++r)
#pragma unroll
        for (int c = 0; c < CT; ++c) acc[r][c] = (f32x16)(0.0f);

    for (int k0 = 0; k0 < K; k0 += 16) {
        // ---- stage A: fp32 -> bf16 hi/lo via v_cvt_pk_bf16_f32 (half the VALU of scalar split) ----
#pragma unroll
        for (int idx = tid; idx < BM * 4; idx += NTHREADS) {
            int row = idx >> 2, kq = idx & 3;
            int grow = m0 + row;
            float4 v = make_float4(0.f, 0.f, 0.f, 0.f);
            if (grow < M) v = *reinterpret_cast<const float4*>(&A[(size_t)grow * K + k0 + kq * 4]);
            uint2 hh, ll;
            hh.x = cvtpk_bf16(v.x, v.y);
            hh.y = cvtpk_bf16(v.z, v.w);
            float h0 = __uint_as_float(hh.x << 16);
            float h1 = __uint_as_float(hh.x & 0xFFFF0000u);
            float h2 = __uint_as_float(hh.y << 16);
            float h3 = __uint_as_float(hh.y & 0xFFFF0000u);
            ll.x = cvtpk_bf16(v.x - h0, v.y - h1);
            ll.y = cvtpk_bf16(v.z - h2, v.w - h3);
            int off = (row >> 5) * 1024 + (kq >> 1) * 512 + (row & 31) * 16 + (kq & 1) * 8;
            *reinterpret_cast<uint2*>(&smem[A_HI + off]) = hh;
            *reinterpret_cast<uint2*>(&smem[A_LO + off]) = ll;
        }
#pragma unroll
        for (int idx = tid; idx < BN * 2; idx += NTHREADS) {
            int n = idx >> 1, kg = idx & 1;
            uint4 vh = *reinterpret_cast<const uint4*>(&Bth[(size_t)n * K + k0 + kg * 8]);
            uint4 vl = *reinterpret_cast<const uint4*>(&Btl[(size_t)n * K + k0 + kg * 8]);
            int off = (n >> 5) * 1024 + kg * 512 + (n & 31) * 16;
            *reinterpret_cast<uint4*>(&smem[B_HI + off]) = vh;
            *reinterpret_cast<uint4*>(&smem[B_LO + off]) = vl;
        }
        __syncthreads();

        short8v ah[RT], al[RT], bh[CT], bl[CT];
#pragma unroll
        for (int r = 0; r < RT; ++r) {
            int off = (wm * RT + r) * 1024 + lane * 16;
            ah[r] = *reinterpret_cast<const short8v*>(&smem[A_HI + off]);
            al[r] = *reinterpret_cast<const short8v*>(&smem[A_LO + off]);
        }
#pragma unroll
        for (int c = 0; c < CT; ++c) {
            int off = (wn * CT + c) * 1024 + lane * 16;
            bh[c] = *reinterpret_cast<const short8v*>(&smem[B_HI + off]);
            bl[c] = *reinterpret_cast<const short8v*>(&smem[B_LO + off]);
        }
#pragma unroll
        for (int r = 0; r < RT; ++r)
#pragma unroll
            for (int c = 0; c < CT; ++c) {
                acc[r][c] = __builtin_amdgcn_mfma_f32_32x32x16_bf16(ah[r], bh[c], acc[r][c], 0, 0, 0);
                acc[r][c] = __builtin_amdgcn_mfma_f32_32x32x16_bf16(al[r], bh[c], acc[r][c], 0, 0, 0);
                acc[r][c] = __builtin_amdgcn_mfma_f32_32x32x16_bf16(ah[r], bl[c], acc[r][c], 0, 0, 0);
            }
        __syncthreads();
    }

    const int lo32 = lane & 31;
    const int hi32 = lane >> 5;
#pragma unroll
    for (int r = 0; r < RT; ++r)
#pragma unroll
        for (int c = 0; c < CT; ++c) {
            int rowbase = m0 + (wm * RT + r) * 32 + 4 * hi32;
            int col = (wn * CT + c) * 32 + lo32;
#pragma unroll
            for (int g = 0; g < 4; ++g)
#pragma unroll
                for (int q = 0; q < 4; ++q) {
                    int row = rowbase + 8 * g + q;
                    if (row < M) C[(size_t)row * BN + col] = f2bf(acc[r][c][g * 4 + q]);
                }
        }
}

// ---------------- gemm2: C_bf16[M,32] = A_bf16[M,128] @ W2; A exact, W2 split (2 MFMA/tile) ----------------
__global__ __launch_bounds__(128) void gemm2_mfma_kernel(const unsigned short* __restrict__ A,
                                                         const unsigned short* __restrict__ Bth,
                                                         const unsigned short* __restrict__ Btl,
                                                         unsigned short* __restrict__ C, int M) {
    constexpr int BM = 128, BN = 32, K = NH;
    constexpr int B_HI = 4096, B_LO = 5120;
    __shared__ __align__(16) unsigned char smem[6144];

    const int tid = threadIdx.x;
    const int lane = tid & 63;
    const int wm = tid >> 6;  // 2 waves: m-split
    const int m0 = blockIdx.x * BM;

    f32x16 acc[2];
    acc[0] = (f32x16)(0.0f);
    acc[1] = (f32x16)(0.0f);

    for (int k0 = 0; k0 < K; k0 += 16) {
#pragma unroll
        for (int i = 0; i < 2; ++i) {
            int idx = tid + i * 128;
            int row = idx >> 1, kg = idx & 1;
            int gr = m0 + row;
            uint4 v = make_uint4(0, 0, 0, 0);
            if (gr < M) v = *reinterpret_cast<const uint4*>(&A[(size_t)gr * K + k0 + kg * 8]);
            int off = (row >> 5) * 1024 + kg * 512 + (row & 31) * 16;
            *reinterpret_cast<uint4*>(&smem[off]) = v;
        }
        if (tid < 64) {
            int n = tid >> 1, kg = tid & 1;
            uint4 vh = *reinterpret_cast<const uint4*>(&Bth[(size_t)n * K + k0 + kg * 8]);
            uint4 vl = *reinterpret_cast<const uint4*>(&Btl[(size_t)n * K + k0 + kg * 8]);
            int off = kg * 512 + n * 16;
            *reinterpret_cast<uint4*>(&smem[B_HI + off]) = vh;
            *reinterpret_cast<uint4*>(&smem[B_LO + off]) = vl;
        }
        __syncthreads();

        short8v a0 = *reinterpret_cast<const short8v*>(&smem[(wm * 2 + 0) * 1024 + lane * 16]);
        short8v a1 = *reinterpret_cast<const short8v*>(&smem[(wm * 2 + 1) * 1024 + lane * 16]);
        short8v bh = *reinterpret_cast<const short8v*>(&smem[B_HI + lane * 16]);
        short8v bl = *reinterpret_cast<const short8v*>(&smem[B_LO + lane * 16]);
        acc[0] = __builtin_amdgcn_mfma_f32_32x32x16_bf16(a0, bh, acc[0], 0, 0, 0);
        acc[0] = __builtin_amdgcn_mfma_f32_32x32x16_bf16(a0, bl, acc[0], 0, 0, 0);
        acc[1] = __builtin_amdgcn_mfma_f32_32x32x16_bf16(a1, bh, acc[1], 0, 0, 0);
        acc[1] = __builtin_amdgcn_mfma_f32_32x32x16_bf16(a1, bl, acc[1], 0, 0, 0);
        __syncthreads();
    }

    const int lo32 = lane & 31;
    const int hi32 = lane >> 5;
#pragma unroll
    for (int r = 0; r < 2; ++r) {
        int rowbase = m0 + (wm * 2 + r) * 32 + 4 * hi32;
#pragma unroll
        for (int g = 0; g < 4; ++g)
#pragma unroll
            for (int q = 0; q < 4; ++q) {
                int row = rowbase + 8 * g + q;
                if (row < M) C[(size_t)row * BN + lo32] = f2bf(acc[r][g * 4 + q]);
            }
    }
}

// ---------------- aggregation (SpMM via CSR, bf16 activations, packed fp32 math) ----------------

// One WAVE per node. 256B bf16 row = 16 lanes x uint4; 4 edge streams x 4-deep
// unroll = 16 gathers in flight (+2-deep mid-tier for deg 8-15).
// v2f accumulators -> v_pk_fma_f32. Fused bias+relu; cvt_pk bf16 out.
__global__ __launch_bounds__(256) void agg_nh_kernel(const unsigned short* __restrict__ support,
                                                     const int* __restrict__ rowptr,
                                                     const int2* __restrict__ pedge,
                                                     const float* __restrict__ bias,
                                                     unsigned short* __restrict__ outh) {
    const int wid = threadIdx.x >> 6;
    const int lane = threadIdx.x & 63;
    const int g = lane >> 4;      // 4 edge streams
    const int f = lane & 15;      // 16B chunk within the 256B row
    const int node = blockIdx.x * 4 + wid;
    const int beg = rowptr[node];
    const int end = rowptr[node + 1];

    v2f a0[4] = {}, a1[4] = {}, a2[4] = {}, a3[4] = {};

    int e = beg + g;
    for (; e + 12 < end; e += 16) {   // this stream: edges e, e+4, e+8, e+12
        int2 e0 = pedge[e];
        int2 e1 = pedge[e + 4];
        int2 e2 = pedge[e + 8];
        int2 e3 = pedge[e + 12];
        uint4 q0 = reinterpret_cast<const uint4*>(&support[(size_t)e0.x * NH])[f];
        uint4 q1 = reinterpret_cast<const uint4*>(&support[(size_t)e1.x * NH])[f];
        uint4 q2 = reinterpret_cast<const uint4*>(&support[(size_t)e2.x * NH])[f];
        uint4 q3 = reinterpret_cast<const uint4*>(&support[(size_t)e3.x * NH])[f];
        float v0 = __int_as_float(e0.y), v1 = __int_as_float(e1.y);
        float v2 = __int_as_float(e2.y), v3 = __int_as_float(e3.y);
        fma8pk(a0, q0, (v2f){v0, v0});
        fma8pk(a1, q1, (v2f){v1, v1});
        fma8pk(a2, q2, (v2f){v2, v2});
        fma8pk(a3, q3, (v2f){v3, v3});
    }
    for (; e + 4 < end; e += 8) {     // mid-tier: 2 edges in flight
        int2 e0 = pedge[e];
        int2 e1 = pedge[e + 4];
        uint4 q0 = reinterpret_cast<const uint4*>(&support[(size_t)e0.x * NH])[f];
        uint4 q1 = reinterpret_cast<const uint4*>(&support[(size_t)e1.x * NH])[f];
        float v0 = __int_as_float(e0.y), v1 = __int_as_float(e1.y);
        fma8pk(a0, q0, (v2f){v0, v0});
        fma8pk(a1, q1, (v2f){v1, v1});
    }
    for (; e < end; e += 4) {
        int2 ed = pedge[e];
        uint4 q = reinterpret_cast<const uint4*>(&support[(size_t)ed.x * NH])[f];
        float v = __int_as_float(ed.y);
        fma8pk(a0, q, (v2f){v, v});
    }

    float r[8];
#pragma unroll
    for (int j = 0; j < 4; ++j) {
        v2f s = a0[j] + a1[j] + a2[j] + a3[j];   // v_pk_add_f32
        float sx = s.x, sy = s.y;
        sx += __shfl_xor(sx, 16);
        sx += __shfl_xor(sx, 32);
        sy += __shfl_xor(sy, 16);
        sy += __shfl_xor(sy, 32);
        r[2 * j] = sx;
        r[2 * j + 1] = sy;
    }

    if (g == 0) {
        float4 b0 = reinterpret_cast<const float4*>(bias)[2 * f];
        float4 b1 = reinterpret_cast<const float4*>(bias)[2 * f + 1];
        float r0 = fmaxf(r[0] + b0.x, 0.f), r1 = fmaxf(r[1] + b0.y, 0.f);
        float r2 = fmaxf(r[2] + b0.z, 0.f), r3 = fmaxf(r[3] + b0.w, 0.f);
        float r4 = fmaxf(r[4] + b1.x, 0.f), r5 = fmaxf(r[5] + b1.y, 0.f);
        float r6 = fmaxf(r[6] + b1.z, 0.f), r7 = fmaxf(r[7] + b1.w, 0.f);
        uint4 o;
        o.x = cvtpk_bf16(r0, r1);
        o.y = cvtpk_bf16(r2, r3);
        o.z = cvtpk_bf16(r4, r5);
        o.w = cvtpk_bf16(r6, r7);
        reinterpret_cast<uint4*>(&outh[(size_t)node * NH])[f] = o;
    }
}

// One WAVE per node. 64B bf16 row = 4 lanes x uint4; 16 edge streams in flight.
// v2f accumulators; fused bias; fp32 out (required output dtype).
__global__ __launch_bounds__(256) void agg_nc_kernel(const unsigned short* __restrict__ support,
                                                     const int* __restrict__ rowptr,
                                                     const int2* __restrict__ pedge,
                                                     const float* __restrict__ bias,
                                                     float* __restrict__ out) {
    const int wid = threadIdx.x >> 6;
    const int lane = threadIdx.x & 63;
    const int g = lane >> 2;      // 16 edge streams
    const int f = lane & 3;       // 16B chunk within the 64B row
    const int node = blockIdx.x * 4 + wid;
    const int beg = rowptr[node];
    const int end = rowptr[node + 1];

    v2f a[4] = {};
    for (int e = beg + g; e < end; e += 16) {
        int2 ed = pedge[e];
        uint4 q = reinterpret_cast<const uint4*>(&support[(size_t)ed.x * NC])[f];
        float v = __int_as_float(ed.y);
        fma8pk(a, q, (v2f){v, v});
    }
    float r[8];
#pragma unroll
    for (int j = 0; j < 4; ++j) {
        float sx = a[j].x, sy = a[j].y;
        sx += __shfl_xor(sx, 4);
        sx += __shfl_xor(sx, 8);
        sx += __shfl_xor(sx, 16);
        sx += __shfl_xor(sx, 32);
        sy += __shfl_xor(sy, 4);
        sy += __shfl_xor(sy, 8);
        sy += __shfl_xor(sy, 16);
        sy += __shfl_xor(sy, 32);
        r[2 * j] = sx;
        r[2 * j + 1] = sy;
    }
    if (g == 0) {
        float4 b0 = reinterpret_cast<const float4*>(bias)[2 * f];
        float4 b1 = reinterpret_cast<const float4*>(bias)[2 * f + 1];
        float4 w0 = make_float4(r[0] + b0.x, r[1] + b0.y, r[2] + b0.z, r[3] + b0.w);
        float4 w1 = make_float4(r[4] + b1.x, r[5] + b1.y, r[6] + b1.z, r[7] + b1.w);
        reinterpret_cast<float4*>(&out[(size_t)node * NC])[2 * f] = w0;
        reinterpret_cast<float4*>(&out[(size_t)node * NC])[2 * f + 1] = w1;
    }
}

// ---------------- launch ----------------

extern "C" void kernel_launch(void* const* d_in, const int* in_sizes, int n_in,
                              void* d_out, int out_size, void* d_ws, size_t ws_size,
                              hipStream_t stream) {
    const float* x = (const float*)d_in[0];
    const int* esrc = (const int*)d_in[1];
    const int* edst = (const int*)d_in[2];
    const float* eval_ = (const float*)d_in[3];
    const float* W1 = (const float*)d_in[4];
    const float* b1 = (const float*)d_in[5];
    const float* W2 = (const float*)d_in[6];
    const float* b2 = (const float*)d_in[7];
    float* out = (float*)d_out;

    // workspace layout (all 16B-aligned)
    char* ws = (char*)d_ws;
    unsigned short* sup = (unsigned short*)(ws + 0);    // 25,600,000 B bf16 support1 / support2
    int* rank = (int*)(ws + 0);                         // 6,400,000 B — ALIASES sup:
                                                        //   written by hist, read by scatter,
                                                        //   dead before gemm1 writes sup
    unsigned short* hbuf = (unsigned short*)(ws + 25600000);  // 25,600,000 B bf16 h
    int* rowptr = (int*)(ws + 51200000);                // 400,128 B
    int* counts = (int*)(ws + 51600128);                // 400,384 B
    int2* pedge = (int2*)(ws + 52000512);               // 12,800,000 B
    int* chunkSums = (int*)(ws + 64800512);             // 512 B
    int* chunkOffs = (int*)(ws + 64801024);             // 512 B
    unsigned short* w1h = (unsigned short*)(ws + 64801536);  // 65,536 B
    unsigned short* w1l = (unsigned short*)(ws + 64867072);  // 65,536 B
    unsigned short* w2h = (unsigned short*)(ws + 64932608);  // 8,192 B
    unsigned short* w2l = (unsigned short*)(ws + 64940800);  // 8,192 B
    (void)ws_size; (void)in_sizes; (void)n_in; (void)out_size;

    // ---- weight conversion (independent of CSR build) ----
    wconv_kernel<<<(NF * NH + NH * NC + 255) / 256, 256, 0, stream>>>(W1, W2, w1h, w1l, w2h, w2l);

    // ---- CSR build: hist(+rank) -> scan -> XCD-pinned atomic-free scatter ----
    zero_int_kernel<<<(NN + 255) / 256, 256, 0, stream>>>(counts, NN);
    hist_kernel<<<(NE + 255) / 256, 256, 0, stream>>>(edst, counts, rank, NE);
    chunk_reduce_kernel<<<SCAN_NCH, 256, 0, stream>>>(counts, chunkSums, NN);
    scan_chunks_kernel<<<1, 64, 0, stream>>>(chunkSums, chunkOffs, rowptr, SCAN_NCH, NN, NE);
    chunk_scan_kernel<<<SCAN_NCH, 256, 0, stream>>>(counts, chunkOffs, rowptr, NN);
    scatter_kernel<<<NSLICES * 8, 256, 0, stream>>>(esrc, edst, eval_, rowptr, rank, pedge, NE);

    // ---- layer 1: sup = bf16(x @ W1); h = bf16(relu(Agg(sup) + b1)) ----
    gemm_mfma_kernel<2, 2, 2, 2, NF><<<(NN + 127) / 128, 256, 0, stream>>>(x, w1h, w1l, sup, NN);
    agg_nh_kernel<<<NN / 4, 256, 0, stream>>>(sup, rowptr, pedge, b1, hbuf);

    // ---- layer 2: sup = bf16(h @ W2); out = Agg(sup) + b2 (fp32) ----
    gemm2_mfma_kernel<<<(NN + 127) / 128, 128, 0, stream>>>(hbuf, w2h, w2l, sup, NN);
    agg_nc_kernel<<<NN / 4, 256, 0, stream>>>(sup, rowptr, pedge, b2, out);
}